// Round 1
// baseline (3658.619 us; speedup 1.0000x reference)
//
#include <hip/hip_runtime.h>

#define NN 100000
#define EE 500000

// ---------- helpers: monotonic float<->uint encoding for atomicMax on floats ----------
__device__ __forceinline__ unsigned enc_f(float x) {
  unsigned b = __float_as_uint(x);
  return (b & 0x80000000u) ? ~b : (b | 0x80000000u);
}
__device__ __forceinline__ float dec_f(unsigned u) {
  unsigned b = (u & 0x80000000u) ? (u & 0x7FFFFFFFu) : ~u;
  return __uint_as_float(b);
}

// ---------- zero fill (graph-capture-safe; ws is poisoned 0xAA every call) ----------
__global__ __launch_bounds__(256) void zero_f4(float4* __restrict__ p, long n4) {
  long i = (long)blockIdx.x * 256 + threadIdx.x;
  if (i < n4) p[i] = make_float4(0.f, 0.f, 0.f, 0.f);
}

// ---------- hs = A[N,128] @ W[128,128], f32, whole W staged in LDS ----------
__global__ __launch_bounds__(256) void gemm128(const float* __restrict__ A,
                                               const float* __restrict__ W,
                                               float* __restrict__ out, int N) {
  __shared__ float sW[128 * 128];
  __shared__ float sA[32 * 128];
  int t = threadIdx.x;
  const float4* W4 = (const float4*)W;
  float4* sW4 = (float4*)sW;
#pragma unroll
  for (int i = 0; i < 16; ++i) sW4[t + 256 * i] = W4[t + 256 * i];
  long row0 = (long)blockIdx.x * 32;  // N is a multiple of 32 (100000)
  const float4* A4 = (const float4*)A;
  float4* sA4 = (float4*)sA;
#pragma unroll
  for (int i = 0; i < 4; ++i) sA4[t + 256 * i] = A4[row0 * 32 + t + 256 * i];
  __syncthreads();
  int cg = t & 31;  // 4-col group
  int rg = t >> 5;  // row group of 4
  float acc[4][4] = {};
  for (int k = 0; k < 128; ++k) {
    float4 w = sW4[k * 32 + cg];
#pragma unroll
    for (int r = 0; r < 4; ++r) {
      float a = sA[(rg * 4 + r) * 128 + k];
      acc[r][0] = fmaf(a, w.x, acc[r][0]);
      acc[r][1] = fmaf(a, w.y, acc[r][1]);
      acc[r][2] = fmaf(a, w.z, acc[r][2]);
      acc[r][3] = fmaf(a, w.w, acc[r][3]);
    }
  }
#pragma unroll
  for (int r = 0; r < 4; ++r) {
    long row = row0 + rg * 4 + r;
    ((float4*)(out + row * 128))[cg] =
        make_float4(acc[r][0], acc[r][1], acc[r][2], acc[r][3]);
  }
}

// ---------- es[n,h] = sum_c hs[n, h*32+c] * av[h*32+c]  (av = att_src flat [128]) ----------
__global__ __launch_bounds__(256) void head_dot(const float* __restrict__ hs,
                                                const float* __restrict__ av,
                                                float* __restrict__ es, int N) {
  int t2 = threadIdx.x & 127;
  int n = blockIdx.x * 2 + (threadIdx.x >> 7);
  if (n >= N) return;
  float v = hs[(long)n * 128 + t2] * av[t2];
#pragma unroll
  for (int m = 1; m <= 16; m <<= 1) v += __shfl_xor(v, m);
  if ((t2 & 31) == 0) es[n * 4 + (t2 >> 5)] = v;
}

// ---------- ed[n,:] = x[n,:] @ Wda[128,4] ----------
__global__ __launch_bounds__(256) void ed_matvec(const float* __restrict__ x,
                                                 const float* __restrict__ Wda,
                                                 float* __restrict__ ed, int N) {
  int t = threadIdx.x & 63;
  int n = blockIdx.x * 4 + (threadIdx.x >> 6);
  if (n >= N) return;
  float x0 = x[(long)n * 128 + t];
  float x1 = x[(long)n * 128 + 64 + t];
  float4 w0 = ((const float4*)Wda)[t];
  float4 w1 = ((const float4*)Wda)[64 + t];
  float p0 = x0 * w0.x + x1 * w1.x;
  float p1 = x0 * w0.y + x1 * w1.y;
  float p2 = x0 * w0.z + x1 * w1.z;
  float p3 = x0 * w0.w + x1 * w1.w;
#pragma unroll
  for (int m = 1; m <= 32; m <<= 1) {
    p0 += __shfl_xor(p0, m);
    p1 += __shfl_xor(p1, m);
    p2 += __shfl_xor(p2, m);
    p3 += __shfl_xor(p3, m);
  }
  if (t == 0) ((float4*)ed)[n] = make_float4(p0, p1, p2, p3);
}

// ---------- fold Wd*a_d -> Wda[128,4]; We*a_e -> Wea[16,4] ----------
__global__ __launch_bounds__(256) void fold_w(const float* __restrict__ Wd,
                                              const float* __restrict__ ad,
                                              const float* __restrict__ We,
                                              const float* __restrict__ ae,
                                              float* __restrict__ Wda,
                                              float* __restrict__ Wea) {
  int t = threadIdx.x;
  if (t < 128) {
    float o[4];
    for (int h = 0; h < 4; ++h) {
      float s = 0.f;
      for (int c = 0; c < 32; ++c) s += Wd[t * 128 + h * 32 + c] * ad[h * 32 + c];
      o[h] = s;
    }
    ((float4*)Wda)[t] = make_float4(o[0], o[1], o[2], o[3]);
  } else if (t < 144) {
    int d = t - 128;
    float o[4];
    for (int h = 0; h < 4; ++h) {
      float s = 0.f;
      for (int c = 0; c < 32; ++c) s += We[d * 128 + h * 32 + c] * ae[h * 32 + c];
      o[h] = s;
    }
    ((float4*)Wea)[d] = make_float4(o[0], o[1], o[2], o[3]);
  }
}

// ---------- alpha = leaky_relu(es[src]+ed[dst]+ea@Wea); store + segment max ----------
__global__ __launch_bounds__(256) void alpha_max(
    const int* __restrict__ src, const int* __restrict__ dst,
    const float* __restrict__ ea, const float* __restrict__ es,
    const float* __restrict__ ed, const float* __restrict__ Wea,
    float* __restrict__ alphabuf, unsigned* __restrict__ mx, int E) {
  int e = blockIdx.x * 256 + threadIdx.x;
  if (e >= E) return;
  int s = src[e], d = dst[e];
  float4 es4 = ((const float4*)es)[s];
  float4 ed4 = ((const float4*)ed)[d];
  float acc[4] = {es4.x + ed4.x, es4.y + ed4.y, es4.z + ed4.z, es4.w + ed4.w};
  const float4* ea4 = (const float4*)(ea + (long)e * 16);
#pragma unroll
  for (int q = 0; q < 4; ++q) {
    float4 a = ea4[q];
    float av[4] = {a.x, a.y, a.z, a.w};
#pragma unroll
    for (int i = 0; i < 4; ++i) {
      float4 w = ((const float4*)Wea)[q * 4 + i];
      acc[0] += av[i] * w.x;
      acc[1] += av[i] * w.y;
      acc[2] += av[i] * w.z;
      acc[3] += av[i] * w.w;
    }
  }
#pragma unroll
  for (int h = 0; h < 4; ++h) {
    float v = acc[h];
    v = (v >= 0.f) ? v : 0.2f * v;  // leaky_relu, slope 0.2
    acc[h] = v;
    atomicMax(&mx[d * 4 + h], enc_f(v));
  }
  ((float4*)alphabuf)[e] = make_float4(acc[0], acc[1], acc[2], acc[3]);
}

// ---------- ex = exp(alpha - mx[dst]); den[dst] += ex (overwrite alphabuf with ex) ----------
__global__ __launch_bounds__(256) void exp_den(const int* __restrict__ dst,
                                               float* __restrict__ alphabuf,
                                               const unsigned* __restrict__ mx,
                                               float* __restrict__ den, int E) {
  int e = blockIdx.x * 256 + threadIdx.x;
  if (e >= E) return;
  int d = dst[e];
  float4 a = ((float4*)alphabuf)[e];
  float m0 = dec_f(mx[d * 4 + 0]);
  float m1 = dec_f(mx[d * 4 + 1]);
  float m2 = dec_f(mx[d * 4 + 2]);
  float m3 = dec_f(mx[d * 4 + 3]);
  float e0 = __expf(a.x - m0);
  float e1 = __expf(a.y - m1);
  float e2 = __expf(a.z - m2);
  float e3 = __expf(a.w - m3);
  ((float4*)alphabuf)[e] = make_float4(e0, e1, e2, e3);
  atomicAdd(&den[d * 4 + 0], e0);
  atomicAdd(&den[d * 4 + 1], e1);
  atomicAdd(&den[d * 4 + 2], e2);
  atomicAdd(&den[d * 4 + 3], e3);
}

// ---------- agg[dst] += (ex/(den[dst]+1e-16)) * hs[src]; 32 threads (float4 lanes) per edge ----------
__global__ __launch_bounds__(256) void aggregate(
    const int* __restrict__ src, const int* __restrict__ dst,
    const float* __restrict__ hs, const float* __restrict__ exb,
    const float* __restrict__ den, float* __restrict__ agg, int E) {
  long gid = (long)blockIdx.x * 256 + threadIdx.x;
  int e = (int)(gid >> 5);
  if (e >= E) return;
  int j = (int)(gid & 31);  // float4 index within the 128-ch row
  int s = src[e], d = dst[e];
  int h = j >> 3;
  float w = exb[e * 4 + h] / (den[d * 4 + h] + 1e-16f);
  float4 v = ((const float4*)(hs + (long)s * 128))[j];
  float* o = agg + (long)d * 128 + j * 4;
  atomicAdd(o + 0, w * v.x);
  atomicAdd(o + 1, w * v.y);
  atomicAdd(o + 2, w * v.z);
  atomicAdd(o + 3, w * v.w);
}

// ---------- out = relu(layernorm(agg + bias) * gamma + beta), one wave per node ----------
__global__ __launch_bounds__(256) void ln_relu(const float* __restrict__ agg,
                                               const float* __restrict__ bias,
                                               const float* __restrict__ gamma,
                                               const float* __restrict__ beta,
                                               float* __restrict__ out, int N) {
  int t = threadIdx.x & 63;
  int n = blockIdx.x * 4 + (threadIdx.x >> 6);
  if (n >= N) return;
  float v0 = agg[(long)n * 128 + t] + bias[t];
  float v1 = agg[(long)n * 128 + 64 + t] + bias[64 + t];
  float s = v0 + v1, sq = v0 * v0 + v1 * v1;
#pragma unroll
  for (int m = 1; m <= 32; m <<= 1) {
    s += __shfl_xor(s, m);
    sq += __shfl_xor(sq, m);
  }
  float mu = s * (1.f / 128.f);
  float var = sq * (1.f / 128.f) - mu * mu;
  float rs = rsqrtf(var + 1e-5f);
  float y0 = (v0 - mu) * rs * gamma[t] + beta[t];
  float y1 = (v1 - mu) * rs * gamma[64 + t] + beta[64 + t];
  out[(long)n * 128 + t] = fmaxf(y0, 0.f);
  out[(long)n * 128 + 64 + t] = fmaxf(y1, 0.f);
}

extern "C" void kernel_launch(void* const* d_in, const int* in_sizes, int n_in,
                              void* d_out, int out_size, void* d_ws,
                              size_t ws_size, hipStream_t stream) {
  const float* x_user = (const float*)d_in[0];
  const float* x_item = (const float*)d_in[1];
  const int* ei_u2i = (const int*)d_in[2];   // [2,E]: su, di
  const int* ei_i2u = (const int*)d_in[3];   // [2,E]: si, du
  const float* ea_u2i = (const float*)d_in[4];
  const float* ea_i2u = (const float*)d_in[5];
  const float* W_src = (const float*)d_in[6];    // [L,2,128,128]
  const float* W_dst = (const float*)d_in[7];    // [L,2,128,128]
  const float* W_edge = (const float*)d_in[8];   // [L,2,16,128]
  const float* att_src = (const float*)d_in[9];  // [L,2,4,32]
  const float* att_dst = (const float*)d_in[10];
  const float* att_edge = (const float*)d_in[11];
  const float* bias = (const float*)d_in[12];  // [L,2,128]
  const float* ln_g = (const float*)d_in[13];  // [L,2,128]
  const float* ln_b = (const float*)d_in[14];

  char* w = (char*)d_ws;
  const size_t NB = (size_t)NN * 128 * sizeof(float);  // 51.2 MB
  float* bufXI = (float*)w; w += NB;  // agg_i -> xi1 (in-place LN)
  float* bufXU = (float*)w; w += NB;  // agg_u -> xu1
  float* hs    = (float*)w; w += NB;  // x_src @ Ws (per conv, reused)
  float* agg2  = (float*)w; w += NB;  // layer-1 user agg
  float* es    = (float*)w; w += (size_t)NN * 4 * sizeof(float);
  float* ed    = (float*)w; w += (size_t)NN * 4 * sizeof(float);
  float* alphabuf = (float*)w; w += (size_t)EE * 4 * sizeof(float);
  unsigned* mx = (unsigned*)w; w += (size_t)NN * 4 * sizeof(unsigned);
  float* den   = (float*)w; w += (size_t)NN * 4 * sizeof(float);
  float* Wda   = (float*)w; w += 128 * 4 * sizeof(float);
  float* Wea   = (float*)w; w += 16 * 4 * sizeof(float);

  auto run_conv = [&](const float* xs, const float* xd, const int* srcI,
                      const int* dstI, const float* ea, int l, int et,
                      float* agg) {
    const float* Ws = W_src + (size_t)(l * 2 + et) * 128 * 128;
    const float* Wd = W_dst + (size_t)(l * 2 + et) * 128 * 128;
    const float* We = W_edge + (size_t)(l * 2 + et) * 16 * 128;
    const float* as_ = att_src + (size_t)(l * 2 + et) * 128;
    const float* ad_ = att_dst + (size_t)(l * 2 + et) * 128;
    const float* ae_ = att_edge + (size_t)(l * 2 + et) * 128;
    gemm128<<<NN / 32, 256, 0, stream>>>(xs, Ws, hs, NN);
    head_dot<<<NN / 2, 256, 0, stream>>>(hs, as_, es, NN);
    fold_w<<<1, 256, 0, stream>>>(Wd, ad_, We, ae_, Wda, Wea);
    ed_matvec<<<NN / 4, 256, 0, stream>>>(xd, Wda, ed, NN);
    // zero mx + den together (adjacent, NN*2 float4s)
    zero_f4<<<(NN * 2 + 255) / 256, 256, 0, stream>>>((float4*)mx, (long)NN * 2);
    alpha_max<<<(EE + 255) / 256, 256, 0, stream>>>(srcI, dstI, ea, es, ed, Wea,
                                                    alphabuf, mx, EE);
    exp_den<<<(EE + 255) / 256, 256, 0, stream>>>(dstI, alphabuf, mx, den, EE);
    zero_f4<<<(NN * 32 + 255) / 256, 256, 0, stream>>>((float4*)agg, (long)NN * 32);
    aggregate<<<(EE * 32) / 256, 256, 0, stream>>>(srcI, dstI, hs, alphabuf, den,
                                                   agg, EE);
  };

  // ---- layer 0 ----
  // u2i: src=user, dst=item; params [0,0]; item LN = gamma[0,1]
  run_conv(x_user, x_item, ei_u2i, ei_u2i + EE, ea_u2i, 0, 0, bufXI);
  ln_relu<<<NN / 4, 256, 0, stream>>>(bufXI, bias + 0 * 128, ln_g + 1 * 128,
                                      ln_b + 1 * 128, bufXI, NN);
  // i2u: src=item, dst=user; params [0,1]; user LN = gamma[0,0]
  run_conv(x_item, x_user, ei_i2u, ei_i2u + EE, ea_i2u, 0, 1, bufXU);
  ln_relu<<<NN / 4, 256, 0, stream>>>(bufXU, bias + 1 * 128, ln_g + 0 * 128,
                                      ln_b + 0 * 128, bufXU, NN);

  // ---- layer 1 ---- (new_i / item path is dead code: reference returns xu only)
  // i2u: src=xi1, dst=xu1; params [1,1]; user LN = gamma[1,0]
  run_conv(bufXI, bufXU, ei_i2u, ei_i2u + EE, ea_i2u, 1, 1, agg2);
  ln_relu<<<NN / 4, 256, 0, stream>>>(agg2, bias + 3 * 128, ln_g + 2 * 128,
                                      ln_b + 2 * 128, (float*)d_out, NN);
}

// Round 2
// 851.179 us; speedup vs baseline: 4.2983x; 4.2983x over previous
//
#include <hip/hip_runtime.h>

#define NN 100000
#define EE 500000

// ---------- zero fill (graph-capture-safe; ws is poisoned 0xAA every call) ----------
__global__ __launch_bounds__(256) void zero_f4(float4* __restrict__ p, long n4) {
  long i = (long)blockIdx.x * 256 + threadIdx.x;
  if (i < n4) p[i] = make_float4(0.f, 0.f, 0.f, 0.f);
}

// ---------- CSR build: histogram ----------
__global__ __launch_bounds__(256) void hist_k(const int* __restrict__ dst,
                                              int* __restrict__ deg, int E) {
  int e = blockIdx.x * 256 + threadIdx.x;
  if (e < E) atomicAdd(&deg[dst[e]], 1);
}

// ---------- CSR build: scan stage 1 (per-block exclusive scan of 1024 elems) ----------
__global__ __launch_bounds__(256) void scan1_k(const int* __restrict__ deg,
                                               int* __restrict__ offs,
                                               int* __restrict__ bsums, int n) {
  __shared__ int sd[256];
  int t = threadIdx.x;
  int idx = blockIdx.x * 1024 + t * 4;
  int v0 = (idx < n) ? deg[idx] : 0;
  int v1 = (idx + 1 < n) ? deg[idx + 1] : 0;
  int v2 = (idx + 2 < n) ? deg[idx + 2] : 0;
  int v3 = (idx + 3 < n) ? deg[idx + 3] : 0;
  int s = v0 + v1 + v2 + v3;
  sd[t] = s;
  __syncthreads();
  for (int off = 1; off < 256; off <<= 1) {
    int x = (t >= off) ? sd[t - off] : 0;
    __syncthreads();
    sd[t] += x;
    __syncthreads();
  }
  int excl = sd[t] - s;
  if (idx < n) offs[idx] = excl;
  if (idx + 1 < n) offs[idx + 1] = excl + v0;
  if (idx + 2 < n) offs[idx + 2] = excl + v0 + v1;
  if (idx + 3 < n) offs[idx + 3] = excl + v0 + v1 + v2;
  if (t == 255) bsums[blockIdx.x] = sd[255];
}

// ---------- CSR build: scan stage 2 (scan the block sums; write total) ----------
__global__ __launch_bounds__(128) void scan2_k(int* __restrict__ bsums, int G,
                                               int* __restrict__ offs_last) {
  __shared__ int sd[128];
  int t = threadIdx.x;
  int v = (t < G) ? bsums[t] : 0;
  sd[t] = v;
  __syncthreads();
  for (int off = 1; off < 128; off <<= 1) {
    int x = (t >= off) ? sd[t - off] : 0;
    __syncthreads();
    sd[t] += x;
    __syncthreads();
  }
  int incl = sd[t];
  int excl = incl - v;
  if (t < G) bsums[t] = excl;
  if (t == G - 1) *offs_last = incl;
}

// ---------- CSR build: scan stage 3 (add block base; mirror into cursor) ----------
__global__ __launch_bounds__(256) void scan3_k(int* __restrict__ offs,
                                               const int* __restrict__ bsums,
                                               int* __restrict__ cursor, int n) {
  int base = bsums[blockIdx.x];
  int idx = blockIdx.x * 1024 + threadIdx.x * 4;
#pragma unroll
  for (int i = 0; i < 4; ++i) {
    int id = idx + i;
    if (id < n) {
      int v = offs[id] + base;
      offs[id] = v;
      cursor[id] = v;
    }
  }
}

// ---------- CSR build: permute edges into dst-sorted order ----------
__global__ __launch_bounds__(256) void permute_k(const int* __restrict__ src,
                                                 const int* __restrict__ dst,
                                                 int* __restrict__ cursor,
                                                 int* __restrict__ ss,
                                                 int* __restrict__ eid, int E) {
  int e = blockIdx.x * 256 + threadIdx.x;
  if (e >= E) return;
  int d = dst[e];
  int k = atomicAdd(&cursor[d], 1);
  ss[k] = src[e];
  eid[k] = e;
}

// ---------- hs = A[N,128] @ W[128,128], f32, whole W staged in LDS ----------
__global__ __launch_bounds__(256) void gemm128(const float* __restrict__ A,
                                               const float* __restrict__ W,
                                               float* __restrict__ out, int N) {
  __shared__ float sW[128 * 128];
  __shared__ float sA[32 * 128];
  int t = threadIdx.x;
  const float4* W4 = (const float4*)W;
  float4* sW4 = (float4*)sW;
#pragma unroll
  for (int i = 0; i < 16; ++i) sW4[t + 256 * i] = W4[t + 256 * i];
  long row0 = (long)blockIdx.x * 32;  // N is a multiple of 32 (100000)
  const float4* A4 = (const float4*)A;
  float4* sA4 = (float4*)sA;
#pragma unroll
  for (int i = 0; i < 4; ++i) sA4[t + 256 * i] = A4[row0 * 32 + t + 256 * i];
  __syncthreads();
  int cg = t & 31;  // 4-col group
  int rg = t >> 5;  // row group of 4
  float acc[4][4] = {};
  for (int k = 0; k < 128; ++k) {
    float4 w = sW4[k * 32 + cg];
#pragma unroll
    for (int r = 0; r < 4; ++r) {
      float a = sA[(rg * 4 + r) * 128 + k];
      acc[r][0] = fmaf(a, w.x, acc[r][0]);
      acc[r][1] = fmaf(a, w.y, acc[r][1]);
      acc[r][2] = fmaf(a, w.z, acc[r][2]);
      acc[r][3] = fmaf(a, w.w, acc[r][3]);
    }
  }
#pragma unroll
  for (int r = 0; r < 4; ++r) {
    long row = row0 + rg * 4 + r;
    ((float4*)(out + row * 128))[cg] =
        make_float4(acc[r][0], acc[r][1], acc[r][2], acc[r][3]);
  }
}

// ---------- es[n,h] = sum_c hs[n, h*32+c] * av[h*32+c] ----------
__global__ __launch_bounds__(256) void head_dot(const float* __restrict__ hs,
                                                const float* __restrict__ av,
                                                float* __restrict__ es, int N) {
  int t2 = threadIdx.x & 127;
  int n = blockIdx.x * 2 + (threadIdx.x >> 7);
  if (n >= N) return;
  float v = hs[(long)n * 128 + t2] * av[t2];
#pragma unroll
  for (int m = 1; m <= 16; m <<= 1) v += __shfl_xor(v, m);
  if ((t2 & 31) == 0) es[n * 4 + (t2 >> 5)] = v;
}

// ---------- ed[n,:] = x[n,:] @ Wda[128,4] ----------
__global__ __launch_bounds__(256) void ed_matvec(const float* __restrict__ x,
                                                 const float* __restrict__ Wda,
                                                 float* __restrict__ ed, int N) {
  int t = threadIdx.x & 63;
  int n = blockIdx.x * 4 + (threadIdx.x >> 6);
  if (n >= N) return;
  float x0 = x[(long)n * 128 + t];
  float x1 = x[(long)n * 128 + 64 + t];
  float4 w0 = ((const float4*)Wda)[t];
  float4 w1 = ((const float4*)Wda)[64 + t];
  float p0 = x0 * w0.x + x1 * w1.x;
  float p1 = x0 * w0.y + x1 * w1.y;
  float p2 = x0 * w0.z + x1 * w1.z;
  float p3 = x0 * w0.w + x1 * w1.w;
#pragma unroll
  for (int m = 1; m <= 32; m <<= 1) {
    p0 += __shfl_xor(p0, m);
    p1 += __shfl_xor(p1, m);
    p2 += __shfl_xor(p2, m);
    p3 += __shfl_xor(p3, m);
  }
  if (t == 0) ((float4*)ed)[n] = make_float4(p0, p1, p2, p3);
}

// ---------- fold Wd*a_d -> Wda[128,4]; We*a_e -> Wea[16,4] ----------
__global__ __launch_bounds__(256) void fold_w(const float* __restrict__ Wd,
                                              const float* __restrict__ ad,
                                              const float* __restrict__ We,
                                              const float* __restrict__ ae,
                                              float* __restrict__ Wda,
                                              float* __restrict__ Wea) {
  int t = threadIdx.x;
  if (t < 128) {
    float o[4];
    for (int h = 0; h < 4; ++h) {
      float s = 0.f;
      for (int c = 0; c < 32; ++c) s += Wd[t * 128 + h * 32 + c] * ad[h * 32 + c];
      o[h] = s;
    }
    ((float4*)Wda)[t] = make_float4(o[0], o[1], o[2], o[3]);
  } else if (t < 144) {
    int d = t - 128;
    float o[4];
    for (int h = 0; h < 4; ++h) {
      float s = 0.f;
      for (int c = 0; c < 32; ++c) s += We[d * 128 + h * 32 + c] * ae[h * 32 + c];
      o[h] = s;
    }
    ((float4*)Wea)[d] = make_float4(o[0], o[1], o[2], o[3]);
  }
}

// ---------- alpha = leaky_relu(es[src]+ed[dst]+ea@Wea); store (edge order) ----------
__global__ __launch_bounds__(256) void alpha_k(
    const int* __restrict__ src, const int* __restrict__ dst,
    const float* __restrict__ ea, const float* __restrict__ es,
    const float* __restrict__ ed, const float* __restrict__ Wea,
    float* __restrict__ alphabuf, int E) {
  int e = blockIdx.x * 256 + threadIdx.x;
  if (e >= E) return;
  int s = src[e], d = dst[e];
  float4 es4 = ((const float4*)es)[s];
  float4 ed4 = ((const float4*)ed)[d];
  float acc[4] = {es4.x + ed4.x, es4.y + ed4.y, es4.z + ed4.z, es4.w + ed4.w};
  const float4* ea4 = (const float4*)(ea + (long)e * 16);
#pragma unroll
  for (int q = 0; q < 4; ++q) {
    float4 a = ea4[q];
    float av[4] = {a.x, a.y, a.z, a.w};
#pragma unroll
    for (int i = 0; i < 4; ++i) {
      float4 w = ((const float4*)Wea)[q * 4 + i];
      acc[0] += av[i] * w.x;
      acc[1] += av[i] * w.y;
      acc[2] += av[i] * w.z;
      acc[3] += av[i] * w.w;
    }
  }
#pragma unroll
  for (int h = 0; h < 4; ++h) {
    float v = acc[h];
    acc[h] = (v >= 0.f) ? v : 0.2f * v;  // leaky_relu, slope 0.2
  }
  ((float4*)alphabuf)[e] = make_float4(acc[0], acc[1], acc[2], acc[3]);
}

// ---------- gather + segment softmax + weighted sum + bias + LN + ReLU ----------
// 32 lanes per dst node (lane j owns channels 4j..4j+3; head h = j>>3).
__global__ __launch_bounds__(256) void gather_ln(
    const int* __restrict__ offs, const int* __restrict__ src_sorted,
    const int* __restrict__ eid_sorted, const float* __restrict__ hs,
    const float* __restrict__ alphabuf, const float* __restrict__ bias,
    const float* __restrict__ gamma, const float* __restrict__ beta,
    float* __restrict__ out, int N) {
  int t = threadIdx.x;
  int j = t & 31;
  int h = j >> 3;
  int n = blockIdx.x * 8 + (t >> 5);
  if (n >= N) return;
  int rs = offs[n], re = offs[n + 1];
  // pass 1: per-head max
  float m = -1e30f;
  for (int k = rs; k < re; ++k)
    m = fmaxf(m, alphabuf[(long)eid_sorted[k] * 4 + h]);
  // pass 2: weighted accumulate + denominator
  float4 acc = make_float4(0.f, 0.f, 0.f, 0.f);
  float den = 0.f;
  for (int k = rs; k < re; ++k) {
    int e = eid_sorted[k];
    int s = src_sorted[k];
    float wv = __expf(alphabuf[(long)e * 4 + h] - m);
    den += wv;
    float4 v = ((const float4*)hs)[(long)s * 32 + j];
    acc.x += wv * v.x;
    acc.y += wv * v.y;
    acc.z += wv * v.z;
    acc.w += wv * v.w;
  }
  float inv = 1.f / (den + 1e-16f);
  float4 b4 = ((const float4*)bias)[j];
  float4 o = make_float4(acc.x * inv + b4.x, acc.y * inv + b4.y,
                         acc.z * inv + b4.z, acc.w * inv + b4.w);
  // LayerNorm over the 128 channels held by this 32-lane group
  float s1 = o.x + o.y + o.z + o.w;
  float s2 = o.x * o.x + o.y * o.y + o.z * o.z + o.w * o.w;
#pragma unroll
  for (int mm = 1; mm <= 16; mm <<= 1) {
    s1 += __shfl_xor(s1, mm);
    s2 += __shfl_xor(s2, mm);
  }
  float mu = s1 * (1.f / 128.f);
  float var = s2 * (1.f / 128.f) - mu * mu;
  float rstd = rsqrtf(var + 1e-5f);
  float4 g4 = ((const float4*)gamma)[j];
  float4 be4 = ((const float4*)beta)[j];
  float4 y;
  y.x = fmaxf((o.x - mu) * rstd * g4.x + be4.x, 0.f);
  y.y = fmaxf((o.y - mu) * rstd * g4.y + be4.y, 0.f);
  y.z = fmaxf((o.z - mu) * rstd * g4.z + be4.z, 0.f);
  y.w = fmaxf((o.w - mu) * rstd * g4.w + be4.w, 0.f);
  ((float4*)out)[(long)n * 32 + j] = y;
}

extern "C" void kernel_launch(void* const* d_in, const int* in_sizes, int n_in,
                              void* d_out, int out_size, void* d_ws,
                              size_t ws_size, hipStream_t stream) {
  const float* x_user = (const float*)d_in[0];
  const float* x_item = (const float*)d_in[1];
  const int* ei_u2i = (const int*)d_in[2];   // [2,E]: su, di
  const int* ei_i2u = (const int*)d_in[3];   // [2,E]: si, du
  const float* ea_u2i = (const float*)d_in[4];
  const float* ea_i2u = (const float*)d_in[5];
  const float* W_src = (const float*)d_in[6];    // [L,2,128,128]
  const float* W_dst = (const float*)d_in[7];    // [L,2,128,128]
  const float* W_edge = (const float*)d_in[8];   // [L,2,16,128]
  const float* att_src = (const float*)d_in[9];  // [L,2,4,32]
  const float* att_dst = (const float*)d_in[10];
  const float* att_edge = (const float*)d_in[11];
  const float* bias = (const float*)d_in[12];  // [L,2,128]
  const float* ln_g = (const float*)d_in[13];  // [L,2,128]
  const float* ln_b = (const float*)d_in[14];

  char* w = (char*)d_ws;
  const size_t NB = (size_t)NN * 128 * sizeof(float);  // 51.2 MB
  float* bufXI = (float*)w; w += NB;
  float* bufXU = (float*)w; w += NB;
  float* hs    = (float*)w; w += NB;
  float* es    = (float*)w; w += (size_t)NN * 4 * sizeof(float);
  float* ed    = (float*)w; w += (size_t)NN * 4 * sizeof(float);
  float* alphabuf = (float*)w; w += (size_t)EE * 4 * sizeof(float);
  float* Wda   = (float*)w; w += 128 * 4 * sizeof(float);
  float* Wea   = (float*)w; w += 256 * sizeof(float);
  // CSR scratch
  int* deg     = (int*)w; w += (size_t)NN * sizeof(int);
  int* cursor  = (int*)w; w += (size_t)NN * sizeof(int);
  int* bsums   = (int*)w; w += 128 * sizeof(int);
  int* offs_u2i = (int*)w; w += (size_t)(NN + 4) * sizeof(int);
  int* offs_i2u = (int*)w; w += (size_t)(NN + 4) * sizeof(int);
  int* ss_u2i  = (int*)w; w += (size_t)EE * sizeof(int);
  int* ei_s_u2i = (int*)w; w += (size_t)EE * sizeof(int);
  int* ss_i2u  = (int*)w; w += (size_t)EE * sizeof(int);
  int* ei_s_i2u = (int*)w; w += (size_t)EE * sizeof(int);

  const int SCAN_G = (NN + 1023) / 1024;  // 98
  const int EG = (EE + 255) / 256;

  auto build_csr = [&](const int* srcI, const int* dstI, int* offs, int* ss,
                       int* eid) {
    zero_f4<<<(NN / 4 + 255) / 256, 256, 0, stream>>>((float4*)deg, NN / 4);
    hist_k<<<EG, 256, 0, stream>>>(dstI, deg, EE);
    scan1_k<<<SCAN_G, 256, 0, stream>>>(deg, offs, bsums, NN);
    scan2_k<<<1, 128, 0, stream>>>(bsums, SCAN_G, offs + NN);
    scan3_k<<<SCAN_G, 256, 0, stream>>>(offs, bsums, cursor, NN);
    permute_k<<<EG, 256, 0, stream>>>(srcI, dstI, cursor, ss, eid, EE);
  };

  build_csr(ei_u2i, ei_u2i + EE, offs_u2i, ss_u2i, ei_s_u2i);
  build_csr(ei_i2u, ei_i2u + EE, offs_i2u, ss_i2u, ei_s_i2u);

  auto run_conv = [&](const float* xs, const float* xd, const int* srcI,
                      const int* dstI, const float* ea, const int* offs,
                      const int* ss, const int* eid, int l, int et,
                      const float* bias_p, const float* g_p, const float* b_p,
                      float* outbuf) {
    const float* Ws = W_src + (size_t)(l * 2 + et) * 128 * 128;
    const float* Wd = W_dst + (size_t)(l * 2 + et) * 128 * 128;
    const float* We = W_edge + (size_t)(l * 2 + et) * 16 * 128;
    const float* as_ = att_src + (size_t)(l * 2 + et) * 128;
    const float* ad_ = att_dst + (size_t)(l * 2 + et) * 128;
    const float* ae_ = att_edge + (size_t)(l * 2 + et) * 128;
    gemm128<<<NN / 32, 256, 0, stream>>>(xs, Ws, hs, NN);
    head_dot<<<NN / 2, 256, 0, stream>>>(hs, as_, es, NN);
    fold_w<<<1, 256, 0, stream>>>(Wd, ad_, We, ae_, Wda, Wea);
    ed_matvec<<<NN / 4, 256, 0, stream>>>(xd, Wda, ed, NN);
    alpha_k<<<EG, 256, 0, stream>>>(srcI, dstI, ea, es, ed, Wea, alphabuf, EE);
    gather_ln<<<(NN + 7) / 8, 256, 0, stream>>>(offs, ss, eid, hs, alphabuf,
                                                bias_p, g_p, b_p, outbuf, NN);
  };

  // ---- layer 0 ----
  // u2i: src=user, dst=item; params [0,0]; item LN = [0,1]
  run_conv(x_user, x_item, ei_u2i, ei_u2i + EE, ea_u2i, offs_u2i, ss_u2i,
           ei_s_u2i, 0, 0, bias + 0 * 128, ln_g + 1 * 128, ln_b + 1 * 128,
           bufXI);
  // i2u: src=item, dst=user; params [0,1]; user LN = [0,0]
  run_conv(x_item, x_user, ei_i2u, ei_i2u + EE, ea_i2u, offs_i2u, ss_i2u,
           ei_s_i2u, 0, 1, bias + 1 * 128, ln_g + 0 * 128, ln_b + 0 * 128,
           bufXU);
  // ---- layer 1 ---- (item path dead: reference returns xu only)
  // i2u: src=xi1, dst=xu1; params [1,1]; user LN = [1,0]
  run_conv(bufXI, bufXU, ei_i2u, ei_i2u + EE, ea_i2u, offs_i2u, ss_i2u,
           ei_s_i2u, 1, 1, bias + 3 * 128, ln_g + 2 * 128, ln_b + 2 * 128,
           (float*)d_out);
}

// Round 3
// 668.374 us; speedup vs baseline: 5.4739x; 1.2735x over previous
//
#include <hip/hip_runtime.h>

#define NN 100000
#define EE 500000
#define LDSW 136  // padded bf16 row stride in LDS (16B-aligned rows, breaks bank conflicts)

typedef __attribute__((ext_vector_type(8))) short v8s;
typedef __attribute__((ext_vector_type(4))) float v4f;

// ---------- bf16 helpers (RNE) ----------
__device__ __forceinline__ short f2b(float f) {
  unsigned u = __float_as_uint(f);
  unsigned r = (u + 0x7FFFu + ((u >> 16) & 1u)) >> 16;
  return (short)r;
}
__device__ __forceinline__ float b2f(short s) {
  return __uint_as_float(((unsigned)(unsigned short)s) << 16);
}

// ---------- zero fill ----------
__global__ __launch_bounds__(256) void zero_f4(float4* __restrict__ p, long n4) {
  long i = (long)blockIdx.x * 256 + threadIdx.x;
  if (i < n4) p[i] = make_float4(0.f, 0.f, 0.f, 0.f);
}

// ---------- f32 -> bf16 convert (4 elems/thread) ----------
__global__ __launch_bounds__(256) void cvt_k(const float* __restrict__ x,
                                             short* __restrict__ o, long n4) {
  long i = (long)blockIdx.x * 256 + threadIdx.x;
  if (i >= n4) return;
  float4 v = ((const float4*)x)[i];
  unsigned long long p = (unsigned long long)(unsigned short)f2b(v.x) |
                         ((unsigned long long)(unsigned short)f2b(v.y) << 16) |
                         ((unsigned long long)(unsigned short)f2b(v.z) << 32) |
                         ((unsigned long long)(unsigned short)f2b(v.w) << 48);
  ((unsigned long long*)o)[i] = p;
}

// ---------- CSR build ----------
__global__ __launch_bounds__(256) void hist_k(const int* __restrict__ dst,
                                              int* __restrict__ deg, int E) {
  int e = blockIdx.x * 256 + threadIdx.x;
  if (e < E) atomicAdd(&deg[dst[e]], 1);
}

__global__ __launch_bounds__(256) void scan1_k(const int* __restrict__ deg,
                                               int* __restrict__ offs,
                                               int* __restrict__ bsums, int n) {
  __shared__ int sd[256];
  int t = threadIdx.x;
  int idx = blockIdx.x * 1024 + t * 4;
  int v0 = (idx < n) ? deg[idx] : 0;
  int v1 = (idx + 1 < n) ? deg[idx + 1] : 0;
  int v2 = (idx + 2 < n) ? deg[idx + 2] : 0;
  int v3 = (idx + 3 < n) ? deg[idx + 3] : 0;
  int s = v0 + v1 + v2 + v3;
  sd[t] = s;
  __syncthreads();
  for (int off = 1; off < 256; off <<= 1) {
    int x = (t >= off) ? sd[t - off] : 0;
    __syncthreads();
    sd[t] += x;
    __syncthreads();
  }
  int excl = sd[t] - s;
  if (idx < n) offs[idx] = excl;
  if (idx + 1 < n) offs[idx + 1] = excl + v0;
  if (idx + 2 < n) offs[idx + 2] = excl + v0 + v1;
  if (idx + 3 < n) offs[idx + 3] = excl + v0 + v1 + v2;
  if (t == 255) bsums[blockIdx.x] = sd[255];
}

__global__ __launch_bounds__(128) void scan2_k(int* __restrict__ bsums, int G,
                                               int* __restrict__ offs_last) {
  __shared__ int sd[128];
  int t = threadIdx.x;
  int v = (t < G) ? bsums[t] : 0;
  sd[t] = v;
  __syncthreads();
  for (int off = 1; off < 128; off <<= 1) {
    int x = (t >= off) ? sd[t - off] : 0;
    __syncthreads();
    sd[t] += x;
    __syncthreads();
  }
  int incl = sd[t];
  if (t < G) bsums[t] = incl - v;
  if (t == G - 1) *offs_last = incl;
}

__global__ __launch_bounds__(256) void scan3_k(int* __restrict__ offs,
                                               const int* __restrict__ bsums,
                                               int* __restrict__ cursor, int n) {
  int base = bsums[blockIdx.x];
  int idx = blockIdx.x * 1024 + threadIdx.x * 4;
#pragma unroll
  for (int i = 0; i < 4; ++i) {
    int id = idx + i;
    if (id < n) {
      int v = offs[id] + base;
      offs[id] = v;
      cursor[id] = v;
    }
  }
}

// permute: edges -> dst-sorted; ss[k]=src, rank[e]=k (inverse perm for alpha scatter)
__global__ __launch_bounds__(256) void permute_k(const int* __restrict__ src,
                                                 const int* __restrict__ dst,
                                                 int* __restrict__ cursor,
                                                 int* __restrict__ ss,
                                                 int* __restrict__ rank, int E) {
  int e = blockIdx.x * 256 + threadIdx.x;
  if (e >= E) return;
  int d = dst[e];
  int k = atomicAdd(&cursor[d], 1);
  ss[k] = src[e];
  rank[e] = k;
}

// ---------- prep: fold Wd*a_d -> Wda[128,4], We*a_e -> Wea[16,4]; W -> Wt bf16 transposed ----------
__global__ __launch_bounds__(256) void prep_k(
    const float* __restrict__ W, const float* __restrict__ Wd,
    const float* __restrict__ ad, const float* __restrict__ We,
    const float* __restrict__ ae, float* __restrict__ Wda,
    float* __restrict__ Wea, short* __restrict__ Wt) {
  int b = blockIdx.x, t = threadIdx.x;
  if (b == 0) {
    if (t < 128) {
      float o[4];
      for (int h = 0; h < 4; ++h) {
        float s = 0.f;
        for (int c = 0; c < 32; ++c)
          s += Wd[t * 128 + h * 32 + c] * ad[h * 32 + c];
        o[h] = s;
      }
      ((float4*)Wda)[t] = make_float4(o[0], o[1], o[2], o[3]);
    } else if (t < 144) {
      int d = t - 128;
      float o[4];
      for (int h = 0; h < 4; ++h) {
        float s = 0.f;
        for (int c = 0; c < 32; ++c)
          s += We[d * 128 + h * 32 + c] * ae[h * 32 + c];
        o[h] = s;
      }
      ((float4*)Wea)[d] = make_float4(o[0], o[1], o[2], o[3]);
    }
  } else {
    int idx = (b - 1) * 256 + t;  // 0..16383
    int k = idx >> 7, n = idx & 127;
    Wt[n * 128 + k] = f2b(W[idx]);  // Wt[col][k]
  }
}

// ---------- MFMA GEMM: hs[N,128](bf16) = A[N,128](bf16) @ W[128,128]; fused es = hs.a_s ----------
// Per wave: one 16-row tile, 8 col-tiles x 4 k-chunks of mfma_f32_16x16x32_bf16.
// A frag: A[m=lane&15][k=(lane>>4)*8+j] -> 16B global load. B frag from Wt (col-major-k) in LDS.
// C/D: col=lane&15, row=(lane>>4)*4+reg.
__global__ __launch_bounds__(256) void gemm_mfma(
    const short* __restrict__ A, const short* __restrict__ Wt,
    const float* __restrict__ a_s, short* __restrict__ hs,
    float* __restrict__ es, int N) {
  __shared__ short sW[128 * LDSW];
  __shared__ short sC[4][16 * LDSW];
  __shared__ float sAs[128];
  int t = threadIdx.x;
  {
    const int4* srcp = (const int4*)Wt;  // 2048 x 16B chunks
    for (int c = t; c < 2048; c += 256) {
      int row = c >> 4, col = c & 15;
      *(int4*)&sW[row * LDSW + col * 8] = srcp[c];
    }
    if (t < 128) sAs[t] = a_s[t];
  }
  __syncthreads();
  int wid = t >> 6, lane = t & 63;
  int tile = blockIdx.x * 4 + wid;
  if (tile * 16 >= N) return;
  long row0 = (long)tile * 16;
  int m = lane & 15, q = lane >> 4;
  v8s af[4];
  const short* arow = A + (row0 + m) * 128 + q * 8;
#pragma unroll
  for (int kc = 0; kc < 4; ++kc) af[kc] = *(const v8s*)(arow + kc * 32);
  v4f zero4 = {0.f, 0.f, 0.f, 0.f};
  v4f acc[8];
#pragma unroll
  for (int ct = 0; ct < 8; ++ct) {
    acc[ct] = zero4;
#pragma unroll
    for (int kc = 0; kc < 4; ++kc) {
      v8s bfr = *(const v8s*)&sW[(ct * 16 + m) * LDSW + kc * 32 + q * 8];
      acc[ct] =
          __builtin_amdgcn_mfma_f32_16x16x32_bf16(af[kc], bfr, acc[ct], 0, 0, 0);
    }
  }
  // stage C tile (wave-private LDS region; wave-internal ordering only)
  short* myC = sC[wid];
#pragma unroll
  for (int ct = 0; ct < 8; ++ct)
#pragma unroll
    for (int r = 0; r < 4; ++r)
      myC[(q * 4 + r) * LDSW + ct * 16 + m] = f2b(acc[ct][r]);
  // write hs rows: lane -> row=lane>>2, 32 shorts (64B)
  {
    int row = lane >> 2, part = lane & 3;
    short* dst = hs + (row0 + row) * 128 + part * 32;
#pragma unroll
    for (int i = 0; i < 4; ++i)
      *(int4*)(dst + i * 8) = *(int4*)&myC[row * LDSW + part * 32 + i * 8];
  }
  // es: lane -> row=lane>>2, h=lane&3
  {
    int row = lane >> 2, h = lane & 3;
    float s = 0.f;
    const short* cr = &myC[row * LDSW + h * 32];
#pragma unroll
    for (int c = 0; c < 32; ++c) s += b2f(cr[c]) * sAs[h * 32 + c];
    es[(row0 + row) * 4 + h] = s;
  }
}

// ---------- ed[n,:] = x[n,:](bf16) @ Wda[128,4] ----------
__global__ __launch_bounds__(256) void ed_matvec(const short* __restrict__ x,
                                                 const float* __restrict__ Wda,
                                                 float* __restrict__ ed, int N) {
  int t = threadIdx.x & 63;
  int n = blockIdx.x * 4 + (threadIdx.x >> 6);
  if (n >= N) return;
  unsigned pp = *(const unsigned*)(x + (long)n * 128 + t * 2);
  float x0 = b2f((short)(pp & 0xFFFF));
  float x1 = b2f((short)(pp >> 16));
  float4 w0 = ((const float4*)Wda)[2 * t];
  float4 w1 = ((const float4*)Wda)[2 * t + 1];
  float p0 = x0 * w0.x + x1 * w1.x;
  float p1 = x0 * w0.y + x1 * w1.y;
  float p2 = x0 * w0.z + x1 * w1.z;
  float p3 = x0 * w0.w + x1 * w1.w;
#pragma unroll
  for (int mm = 1; mm <= 32; mm <<= 1) {
    p0 += __shfl_xor(p0, mm);
    p1 += __shfl_xor(p1, mm);
    p2 += __shfl_xor(p2, mm);
    p3 += __shfl_xor(p3, mm);
  }
  if (t == 0) ((float4*)ed)[n] = make_float4(p0, p1, p2, p3);
}

// ---------- alpha = leaky_relu(es[src]+ed[dst]+ea@Wea); scatter to sorted position ----------
__global__ __launch_bounds__(256) void alpha_k(
    const int* __restrict__ src, const int* __restrict__ dst,
    const int* __restrict__ rank, const float* __restrict__ ea,
    const float* __restrict__ es, const float* __restrict__ ed,
    const float* __restrict__ Wea, float* __restrict__ alphabuf, int E) {
  int e = blockIdx.x * 256 + threadIdx.x;
  if (e >= E) return;
  int s = src[e], d = dst[e];
  float4 es4 = ((const float4*)es)[s];
  float4 ed4 = ((const float4*)ed)[d];
  float acc[4] = {es4.x + ed4.x, es4.y + ed4.y, es4.z + ed4.z, es4.w + ed4.w};
  const float4* ea4 = (const float4*)(ea + (long)e * 16);
#pragma unroll
  for (int qq = 0; qq < 4; ++qq) {
    float4 a = ea4[qq];
    float av[4] = {a.x, a.y, a.z, a.w};
#pragma unroll
    for (int i = 0; i < 4; ++i) {
      float4 w = ((const float4*)Wea)[qq * 4 + i];
      acc[0] += av[i] * w.x;
      acc[1] += av[i] * w.y;
      acc[2] += av[i] * w.z;
      acc[3] += av[i] * w.w;
    }
  }
#pragma unroll
  for (int h = 0; h < 4; ++h) {
    float v = acc[h];
    acc[h] = (v >= 0.f) ? v : 0.2f * v;
  }
  ((float4*)alphabuf)[rank[e]] = make_float4(acc[0], acc[1], acc[2], acc[3]);
}

// ---------- gather: online segment-softmax + weighted sum + bias + LN + ReLU ----------
// 32 lanes per dst node; lane j owns channels 4j..4j+3; head h=j>>3.
template <bool OUT_BF16>
__global__ __launch_bounds__(256) void gather_ln(
    const int* __restrict__ offs, const int* __restrict__ ss,
    const short* __restrict__ hs, const float* __restrict__ alphas,
    const float* __restrict__ bias, const float* __restrict__ gamma,
    const float* __restrict__ beta, void* __restrict__ outp, int N) {
  int t = threadIdx.x;
  int j = t & 31, h = j >> 3;
  int n = blockIdx.x * 8 + (t >> 5);
  if (n >= N) return;
  int rs = offs[n], re = offs[n + 1];
  float m = -1e30f, den = 0.f;
  float a0 = 0.f, a1 = 0.f, a2 = 0.f, a3 = 0.f;
  for (int k = rs; k < re; ++k) {
    int s = ss[k];
    float a = alphas[(long)k * 4 + h];
    unsigned long long pp =
        *(const unsigned long long*)(hs + (long)s * 128 + j * 4);
    float v0 = b2f((short)(pp & 0xFFFF));
    float v1 = b2f((short)((pp >> 16) & 0xFFFF));
    float v2 = b2f((short)((pp >> 32) & 0xFFFF));
    float v3 = b2f((short)(pp >> 48));
    float nm = fmaxf(m, a);
    float c = __expf(m - nm);   // 1 when max unchanged
    float w = __expf(a - nm);
    m = nm;
    den = den * c + w;
    a0 = a0 * c + w * v0;
    a1 = a1 * c + w * v1;
    a2 = a2 * c + w * v2;
    a3 = a3 * c + w * v3;
  }
  float inv = 1.f / (den + 1e-16f);
  float4 b4 = ((const float4*)bias)[j];
  float o0 = a0 * inv + b4.x, o1 = a1 * inv + b4.y;
  float o2 = a2 * inv + b4.z, o3 = a3 * inv + b4.w;
  float s1 = o0 + o1 + o2 + o3;
  float s2 = o0 * o0 + o1 * o1 + o2 * o2 + o3 * o3;
#pragma unroll
  for (int mm = 1; mm <= 16; mm <<= 1) {
    s1 += __shfl_xor(s1, mm);
    s2 += __shfl_xor(s2, mm);
  }
  float mu = s1 * (1.f / 128.f);
  float var = s2 * (1.f / 128.f) - mu * mu;
  float rstd = rsqrtf(var + 1e-5f);
  float4 g4 = ((const float4*)gamma)[j];
  float4 be4 = ((const float4*)beta)[j];
  float y0 = fmaxf((o0 - mu) * rstd * g4.x + be4.x, 0.f);
  float y1 = fmaxf((o1 - mu) * rstd * g4.y + be4.y, 0.f);
  float y2 = fmaxf((o2 - mu) * rstd * g4.z + be4.z, 0.f);
  float y3 = fmaxf((o3 - mu) * rstd * g4.w + be4.w, 0.f);
  if (OUT_BF16) {
    unsigned long long p = (unsigned long long)(unsigned short)f2b(y0) |
                           ((unsigned long long)(unsigned short)f2b(y1) << 16) |
                           ((unsigned long long)(unsigned short)f2b(y2) << 32) |
                           ((unsigned long long)(unsigned short)f2b(y3) << 48);
    ((unsigned long long*)outp)[(long)n * 32 + j] = p;
  } else {
    ((float4*)outp)[(long)n * 32 + j] = make_float4(y0, y1, y2, y3);
  }
}

extern "C" void kernel_launch(void* const* d_in, const int* in_sizes, int n_in,
                              void* d_out, int out_size, void* d_ws,
                              size_t ws_size, hipStream_t stream) {
  const float* x_user = (const float*)d_in[0];
  const float* x_item = (const float*)d_in[1];
  const int* ei_u2i = (const int*)d_in[2];
  const int* ei_i2u = (const int*)d_in[3];
  const float* ea_u2i = (const float*)d_in[4];
  const float* ea_i2u = (const float*)d_in[5];
  const float* W_src = (const float*)d_in[6];
  const float* W_dst = (const float*)d_in[7];
  const float* W_edge = (const float*)d_in[8];
  const float* att_src = (const float*)d_in[9];
  const float* att_dst = (const float*)d_in[10];
  const float* att_edge = (const float*)d_in[11];
  const float* bias = (const float*)d_in[12];
  const float* ln_g = (const float*)d_in[13];
  const float* ln_b = (const float*)d_in[14];

  char* w = (char*)d_ws;
  auto alloc = [&](size_t bytes) {
    void* p = w;
    w += (bytes + 255) & ~(size_t)255;
    return p;
  };
  const size_t NBH = (size_t)NN * 128 * sizeof(short);  // 25.6 MB
  short* xbU = (short*)alloc(NBH);
  short* xbI = (short*)alloc(NBH);
  short* bufXI = (short*)alloc(NBH);
  short* bufXU = (short*)alloc(NBH);
  short* hs = (short*)alloc(NBH);
  float* es = (float*)alloc((size_t)NN * 4 * sizeof(float));
  float* ed = (float*)alloc((size_t)NN * 4 * sizeof(float));
  float* alphabuf = (float*)alloc((size_t)EE * 4 * sizeof(float));
  short* Wt = (short*)alloc(128 * 128 * sizeof(short));
  float* Wda = (float*)alloc(128 * 4 * sizeof(float));
  float* Wea = (float*)alloc(16 * 4 * sizeof(float));
  int* deg = (int*)alloc((size_t)NN * sizeof(int));
  int* cursor = (int*)alloc((size_t)NN * sizeof(int));
  int* bsums = (int*)alloc(512);
  int* offs_u2i = (int*)alloc((size_t)(NN + 4) * sizeof(int));
  int* offs_i2u = (int*)alloc((size_t)(NN + 4) * sizeof(int));
  int* ss_u2i = (int*)alloc((size_t)EE * sizeof(int));
  int* rk_u2i = (int*)alloc((size_t)EE * sizeof(int));
  int* ss_i2u = (int*)alloc((size_t)EE * sizeof(int));
  int* rk_i2u = (int*)alloc((size_t)EE * sizeof(int));

  const int SCAN_G = (NN + 1023) / 1024;
  const int EG = (EE + 255) / 256;

  // input feature conversion to bf16
  cvt_k<<<(NN * 32 + 255) / 256, 256, 0, stream>>>(x_user, xbU, (long)NN * 32);
  cvt_k<<<(NN * 32 + 255) / 256, 256, 0, stream>>>(x_item, xbI, (long)NN * 32);

  auto build_csr = [&](const int* srcI, const int* dstI, int* offs, int* ss,
                       int* rank) {
    zero_f4<<<(NN / 4 + 255) / 256, 256, 0, stream>>>((float4*)deg, NN / 4);
    hist_k<<<EG, 256, 0, stream>>>(dstI, deg, EE);
    scan1_k<<<SCAN_G, 256, 0, stream>>>(deg, offs, bsums, NN);
    scan2_k<<<1, 128, 0, stream>>>(bsums, SCAN_G, offs + NN);
    scan3_k<<<SCAN_G, 256, 0, stream>>>(offs, bsums, cursor, NN);
    permute_k<<<EG, 256, 0, stream>>>(srcI, dstI, cursor, ss, rank, EE);
  };
  build_csr(ei_u2i, ei_u2i + EE, offs_u2i, ss_u2i, rk_u2i);
  build_csr(ei_i2u, ei_i2u + EE, offs_i2u, ss_i2u, rk_i2u);

  auto run_conv = [&](const short* xs, const short* xd, const int* srcI,
                      const int* dstI, const int* rank, const float* ea,
                      const int* offs, const int* ss, int l, int et,
                      const float* bias_p, const float* g_p, const float* b_p,
                      void* outbuf, bool out_bf16) {
    const float* Ws = W_src + (size_t)(l * 2 + et) * 128 * 128;
    const float* Wd = W_dst + (size_t)(l * 2 + et) * 128 * 128;
    const float* We = W_edge + (size_t)(l * 2 + et) * 16 * 128;
    const float* as_ = att_src + (size_t)(l * 2 + et) * 128;
    const float* ad_ = att_dst + (size_t)(l * 2 + et) * 128;
    const float* ae_ = att_edge + (size_t)(l * 2 + et) * 128;
    prep_k<<<65, 256, 0, stream>>>(Ws, Wd, ad_, We, ae_, Wda, Wea, Wt);
    gemm_mfma<<<(NN / 16 + 3) / 4, 256, 0, stream>>>(xs, Wt, as_, hs, es, NN);
    ed_matvec<<<NN / 4, 256, 0, stream>>>(xd, Wda, ed, NN);
    alpha_k<<<EG, 256, 0, stream>>>(srcI, dstI, rank, ea, es, ed, Wea, alphabuf,
                                    EE);
    if (out_bf16)
      gather_ln<true><<<(NN + 7) / 8, 256, 0, stream>>>(
          offs, ss, hs, alphabuf, bias_p, g_p, b_p, outbuf, NN);
    else
      gather_ln<false><<<(NN + 7) / 8, 256, 0, stream>>>(
          offs, ss, hs, alphabuf, bias_p, g_p, b_p, outbuf, NN);
  };

  // ---- layer 0 ----
  run_conv(xbU, xbI, ei_u2i, ei_u2i + EE, rk_u2i, ea_u2i, offs_u2i, ss_u2i, 0,
           0, bias + 0 * 128, ln_g + 1 * 128, ln_b + 1 * 128, bufXI, true);
  run_conv(xbI, xbU, ei_i2u, ei_i2u + EE, rk_i2u, ea_i2u, offs_i2u, ss_i2u, 0,
           1, bias + 1 * 128, ln_g + 0 * 128, ln_b + 0 * 128, bufXU, true);
  // ---- layer 1 ---- (item path dead: reference returns xu only)
  run_conv(bufXI, bufXU, ei_i2u, ei_i2u + EE, rk_i2u, ea_i2u, offs_i2u, ss_i2u,
           1, 1, bias + 3 * 128, ln_g + 2 * 128, ln_b + 2 * 128, d_out, false);
}

// Round 4
// 600.615 us; speedup vs baseline: 6.0915x; 1.1128x over previous
//
#include <hip/hip_runtime.h>

#define NN 100000
#define EE 500000
#define LDSW 136  // padded bf16 row stride in LDS

typedef __attribute__((ext_vector_type(8))) short v8s;
typedef __attribute__((ext_vector_type(4))) float v4f;

// ---------- bf16 helpers (RNE) ----------
__device__ __forceinline__ short f2b(float f) {
  unsigned u = __float_as_uint(f);
  unsigned r = (u + 0x7FFFu + ((u >> 16) & 1u)) >> 16;
  return (short)r;
}
__device__ __forceinline__ float b2f(short s) {
  return __uint_as_float(((unsigned)(unsigned short)s) << 16);
}

// ---------- zero fill ----------
__global__ __launch_bounds__(256) void zero_f4(float4* __restrict__ p, long n4) {
  long i = (long)blockIdx.x * 256 + threadIdx.x;
  if (i < n4) p[i] = make_float4(0.f, 0.f, 0.f, 0.f);
}

// ---------- CSR build ----------
__global__ __launch_bounds__(256) void hist_k(const int* __restrict__ dst,
                                              int* __restrict__ deg, int E) {
  int e = blockIdx.x * 256 + threadIdx.x;
  if (e < E) atomicAdd(&deg[dst[e]], 1);
}

__global__ __launch_bounds__(256) void scan1_k(const int* __restrict__ deg,
                                               int* __restrict__ offs,
                                               int* __restrict__ bsums, int n) {
  __shared__ int sd[256];
  int t = threadIdx.x;
  int idx = blockIdx.x * 1024 + t * 4;
  int v0 = (idx < n) ? deg[idx] : 0;
  int v1 = (idx + 1 < n) ? deg[idx + 1] : 0;
  int v2 = (idx + 2 < n) ? deg[idx + 2] : 0;
  int v3 = (idx + 3 < n) ? deg[idx + 3] : 0;
  int s = v0 + v1 + v2 + v3;
  sd[t] = s;
  __syncthreads();
  for (int off = 1; off < 256; off <<= 1) {
    int x = (t >= off) ? sd[t - off] : 0;
    __syncthreads();
    sd[t] += x;
    __syncthreads();
  }
  int excl = sd[t] - s;
  if (idx < n) offs[idx] = excl;
  if (idx + 1 < n) offs[idx + 1] = excl + v0;
  if (idx + 2 < n) offs[idx + 2] = excl + v0 + v1;
  if (idx + 3 < n) offs[idx + 3] = excl + v0 + v1 + v2;
  if (t == 255) bsums[blockIdx.x] = sd[255];
}

__global__ __launch_bounds__(128) void scan2_k(int* __restrict__ bsums, int G,
                                               int* __restrict__ offs_last) {
  __shared__ int sd[128];
  int t = threadIdx.x;
  int v = (t < G) ? bsums[t] : 0;
  sd[t] = v;
  __syncthreads();
  for (int off = 1; off < 128; off <<= 1) {
    int x = (t >= off) ? sd[t - off] : 0;
    __syncthreads();
    sd[t] += x;
    __syncthreads();
  }
  int incl = sd[t];
  if (t < G) bsums[t] = incl - v;
  if (t == G - 1) *offs_last = incl;
}

__global__ __launch_bounds__(256) void scan3_k(int* __restrict__ offs,
                                               const int* __restrict__ bsums,
                                               int* __restrict__ cursor, int n) {
  int base = bsums[blockIdx.x];
  int idx = blockIdx.x * 1024 + threadIdx.x * 4;
#pragma unroll
  for (int i = 0; i < 4; ++i) {
    int id = idx + i;
    if (id < n) {
      int v = offs[id] + base;
      offs[id] = v;
      cursor[id] = v;
    }
  }
}

__global__ __launch_bounds__(256) void permute_k(const int* __restrict__ src,
                                                 const int* __restrict__ dst,
                                                 int* __restrict__ cursor,
                                                 int* __restrict__ ss,
                                                 int* __restrict__ rank, int E) {
  int e = blockIdx.x * 256 + threadIdx.x;
  if (e >= E) return;
  int d = dst[e];
  int k = atomicAdd(&cursor[d], 1);
  ss[k] = src[e];
  rank[e] = k;
}

// ---------- prep (per GEMM): Wt bf16 transpose; foldB16[128][16] = [Was | Wda | 0];
//            Wea[16][4] f32; optional WdaF32[128][4] ----------
__global__ __launch_bounds__(256) void prep_k(
    const float* __restrict__ W,      // Ws for transpose + Was fold
    const float* __restrict__ as_,    // att_src fold vec [128]
    const float* __restrict__ Wd,     // Wd for ed fold
    const float* __restrict__ ad_,    // att_dst fold vec [128]
    const float* __restrict__ We, const float* __restrict__ ae_,
    short* __restrict__ Wt, short* __restrict__ foldB16,
    float* __restrict__ Wea, float* __restrict__ WdaF32) {
  int b = blockIdx.x, t = threadIdx.x;
  if (b < 64) {
    int idx = b * 256 + t;  // 0..16383
    int k = idx >> 7, n = idx & 127;
    Wt[n * 128 + k] = f2b(W[idx]);  // Wt[col][k]
    return;
  }
  if (t < 128) {
    // Was row t
#pragma unroll
    for (int h = 0; h < 4; ++h) {
      float s = 0.f;
      for (int c = 0; c < 32; ++c) s += W[t * 128 + h * 32 + c] * as_[h * 32 + c];
      foldB16[t * 16 + h] = f2b(s);
    }
#pragma unroll
    for (int j = 8; j < 16; ++j) foldB16[t * 16 + j] = 0;
  } else {
    int k = t - 128;
    float o[4];
#pragma unroll
    for (int h = 0; h < 4; ++h) {
      float s = 0.f;
      for (int c = 0; c < 32; ++c) s += Wd[k * 128 + h * 32 + c] * ad_[h * 32 + c];
      o[h] = s;
      foldB16[k * 16 + 4 + h] = f2b(s);
    }
    if (WdaF32) ((float4*)WdaF32)[k] = make_float4(o[0], o[1], o[2], o[3]);
    if (k < 16) {
      float w[4];
#pragma unroll
      for (int h = 0; h < 4; ++h) {
        float s = 0.f;
        for (int c = 0; c < 32; ++c) s += We[k * 128 + h * 32 + c] * ae_[h * 32 + c];
        w[h] = s;
      }
      ((float4*)Wea)[k] = make_float4(w[0], w[1], w[2], w[3]);
    }
  }
}

// ---------- fused GEMM: hs = A@W (bf16 out), es = A@Was, ed = A@Wda (one extra MFMA/kc) ----------
template <bool A_F32, bool STORE_ED>
__global__ __launch_bounds__(256) void gemm_fused(
    const void* __restrict__ Ap, const short* __restrict__ Wt,
    const short* __restrict__ foldB16, short* __restrict__ hs,
    float* __restrict__ es, float* __restrict__ ed, int N) {
  __shared__ short sW[128 * LDSW];
  __shared__ short sF[128 * 16];
  __shared__ short sC[4][16 * LDSW];
  int t = threadIdx.x;
  {
    const int4* wp = (const int4*)Wt;
    for (int c = t; c < 2048; c += 256) {
      int row = c >> 4, col = c & 15;
      *(int4*)&sW[row * LDSW + col * 8] = wp[c];
    }
    ((int4*)sF)[t] = ((const int4*)foldB16)[t];  // 4096B
  }
  __syncthreads();
  int wid = t >> 6, lane = t & 63;
  long tile = (long)blockIdx.x * 4 + wid;
  if (tile * 16 >= N) return;
  long row0 = tile * 16;
  int m = lane & 15, q = lane >> 4;
  v8s af[4];
  if (A_F32) {
    const float* arow = (const float*)Ap + (row0 + m) * 128 + q * 8;
#pragma unroll
    for (int kc = 0; kc < 4; ++kc) {
      float4 lo = *(const float4*)(arow + kc * 32);
      float4 hi = *(const float4*)(arow + kc * 32 + 4);
      v8s f;
      f[0] = f2b(lo.x); f[1] = f2b(lo.y); f[2] = f2b(lo.z); f[3] = f2b(lo.w);
      f[4] = f2b(hi.x); f[5] = f2b(hi.y); f[6] = f2b(hi.z); f[7] = f2b(hi.w);
      af[kc] = f;
    }
  } else {
    const short* arow = (const short*)Ap + (row0 + m) * 128 + q * 8;
#pragma unroll
    for (int kc = 0; kc < 4; ++kc) af[kc] = *(const v8s*)(arow + kc * 32);
  }
  // fold B fragments (cols: 0-3 Was, 4-7 Wda, 8-15 zero)
  v8s ff[4];
#pragma unroll
  for (int kc = 0; kc < 4; ++kc) {
    v8s f;
#pragma unroll
    for (int j = 0; j < 8; ++j) f[j] = sF[(kc * 32 + q * 8 + j) * 16 + m];
    ff[kc] = f;
  }
  v4f zero4 = {0.f, 0.f, 0.f, 0.f};
  v4f accf = zero4;
#pragma unroll
  for (int kc = 0; kc < 4; ++kc)
    accf = __builtin_amdgcn_mfma_f32_16x16x32_bf16(af[kc], ff[kc], accf, 0, 0, 0);
  v4f acc[8];
#pragma unroll
  for (int ct = 0; ct < 8; ++ct) {
    acc[ct] = zero4;
#pragma unroll
    for (int kc = 0; kc < 4; ++kc) {
      v8s bfr = *(const v8s*)&sW[(ct * 16 + m) * LDSW + kc * 32 + q * 8];
      acc[ct] =
          __builtin_amdgcn_mfma_f32_16x16x32_bf16(af[kc], bfr, acc[ct], 0, 0, 0);
    }
  }
  // es / ed from fold accumulator: D[row=q*4+r][col=m]
#pragma unroll
  for (int r = 0; r < 4; ++r) {
    long row = row0 + q * 4 + r;
    if (m < 4)
      es[row * 4 + m] = accf[r];
    else if (STORE_ED && m < 8)
      ed[row * 4 + (m - 4)] = accf[r];
  }
  // stage C tile -> bf16, then coalesced hs write
  short* myC = sC[wid];
#pragma unroll
  for (int ct = 0; ct < 8; ++ct)
#pragma unroll
    for (int r = 0; r < 4; ++r)
      myC[(q * 4 + r) * LDSW + ct * 16 + m] = f2b(acc[ct][r]);
  {
    int row = lane >> 2, part = lane & 3;
    short* dst = hs + (row0 + row) * 128 + part * 32;
#pragma unroll
    for (int i = 0; i < 4; ++i)
      *(int4*)(dst + i * 8) = *(int4*)&myC[row * LDSW + part * 32 + i * 8];
  }
}

// ---------- alpha: w = exp(leaky_relu(es[src]+ed[dst]+ea@Wea)); pack bf16x4 -> wbuf[rank] ----------
__global__ __launch_bounds__(256) void alpha_k(
    const int* __restrict__ src, const int* __restrict__ dst,
    const int* __restrict__ rank, const float* __restrict__ ea,
    const float* __restrict__ es, const float* __restrict__ ed,
    const float* __restrict__ Wea, unsigned long long* __restrict__ wbuf,
    int E) {
  int e = blockIdx.x * 256 + threadIdx.x;
  if (e >= E) return;
  int s = src[e], d = dst[e];
  float4 es4 = ((const float4*)es)[s];
  float4 ed4 = ((const float4*)ed)[d];
  float acc[4] = {es4.x + ed4.x, es4.y + ed4.y, es4.z + ed4.z, es4.w + ed4.w};
  const float4* ea4 = (const float4*)(ea + (long)e * 16);
#pragma unroll
  for (int qq = 0; qq < 4; ++qq) {
    float4 a = ea4[qq];
    float av[4] = {a.x, a.y, a.z, a.w};
#pragma unroll
    for (int i = 0; i < 4; ++i) {
      float4 w = ((const float4*)Wea)[qq * 4 + i];
      acc[0] += av[i] * w.x;
      acc[1] += av[i] * w.y;
      acc[2] += av[i] * w.z;
      acc[3] += av[i] * w.w;
    }
  }
  unsigned long long p = 0;
#pragma unroll
  for (int h = 0; h < 4; ++h) {
    float v = acc[h];
    v = (v >= 0.f) ? v : 0.2f * v;
    float w = __expf(v);  // alphas are O(1): no max-subtraction needed in f32
    p |= ((unsigned long long)(unsigned short)f2b(w)) << (16 * h);
  }
  wbuf[rank[e]] = p;
}

// ---------- gather: weighted sum (pre-exp'd w) + bias + LN + ReLU (+ fused next-layer ed) ----------
template <bool OUT_BF16, bool ED_FUSE>
__global__ __launch_bounds__(256) void gather_ln(
    const int* __restrict__ offs, const int* __restrict__ ss,
    const short* __restrict__ hs, const unsigned long long* __restrict__ wbuf,
    const float* __restrict__ bias, const float* __restrict__ gamma,
    const float* __restrict__ beta, void* __restrict__ outp,
    const float* __restrict__ WdaN, float* __restrict__ edN, int N) {
  int t = threadIdx.x;
  int j = t & 31, h = j >> 3;
  int n = blockIdx.x * 8 + (t >> 5);
  if (n >= N) return;
  int rs = offs[n], re = offs[n + 1];
  float den = 0.f;
  float a0 = 0.f, a1 = 0.f, a2 = 0.f, a3 = 0.f;
  for (int k = rs; k < re; ++k) {
    int s = ss[k];
    float w = b2f((short)(wbuf[k] >> (16 * h)));
    unsigned long long pp =
        *(const unsigned long long*)(hs + (long)s * 128 + j * 4);
    float v0 = b2f((short)(pp & 0xFFFF));
    float v1 = b2f((short)((pp >> 16) & 0xFFFF));
    float v2 = b2f((short)((pp >> 32) & 0xFFFF));
    float v3 = b2f((short)(pp >> 48));
    den += w;
    a0 += w * v0;
    a1 += w * v1;
    a2 += w * v2;
    a3 += w * v3;
  }
  float inv = 1.f / (den + 1e-16f);
  float4 b4 = ((const float4*)bias)[j];
  float o0 = a0 * inv + b4.x, o1 = a1 * inv + b4.y;
  float o2 = a2 * inv + b4.z, o3 = a3 * inv + b4.w;
  float s1 = o0 + o1 + o2 + o3;
  float s2 = o0 * o0 + o1 * o1 + o2 * o2 + o3 * o3;
#pragma unroll
  for (int mm = 1; mm <= 16; mm <<= 1) {
    s1 += __shfl_xor(s1, mm);
    s2 += __shfl_xor(s2, mm);
  }
  float mu = s1 * (1.f / 128.f);
  float var = s2 * (1.f / 128.f) - mu * mu;
  float rstd = rsqrtf(var + 1e-5f);
  float4 g4 = ((const float4*)gamma)[j];
  float4 be4 = ((const float4*)beta)[j];
  float y0 = fmaxf((o0 - mu) * rstd * g4.x + be4.x, 0.f);
  float y1 = fmaxf((o1 - mu) * rstd * g4.y + be4.y, 0.f);
  float y2 = fmaxf((o2 - mu) * rstd * g4.z + be4.z, 0.f);
  float y3 = fmaxf((o3 - mu) * rstd * g4.w + be4.w, 0.f);
  if (OUT_BF16) {
    unsigned long long p = (unsigned long long)(unsigned short)f2b(y0) |
                           ((unsigned long long)(unsigned short)f2b(y1) << 16) |
                           ((unsigned long long)(unsigned short)f2b(y2) << 32) |
                           ((unsigned long long)(unsigned short)f2b(y3) << 48);
    ((unsigned long long*)outp)[(long)n * 32 + j] = p;
  } else {
    ((float4*)outp)[(long)n * 32 + j] = make_float4(y0, y1, y2, y3);
  }
  if (ED_FUSE) {
    float yv[4] = {y0, y1, y2, y3};
    float e0 = 0.f, e1 = 0.f, e2 = 0.f, e3 = 0.f;
#pragma unroll
    for (int r = 0; r < 4; ++r) {
      float4 wr = ((const float4*)WdaN)[j * 4 + r];
      e0 += yv[r] * wr.x;
      e1 += yv[r] * wr.y;
      e2 += yv[r] * wr.z;
      e3 += yv[r] * wr.w;
    }
#pragma unroll
    for (int mm = 1; mm <= 16; mm <<= 1) {
      e0 += __shfl_xor(e0, mm);
      e1 += __shfl_xor(e1, mm);
      e2 += __shfl_xor(e2, mm);
      e3 += __shfl_xor(e3, mm);
    }
    if (j == 0) ((float4*)edN)[n] = make_float4(e0, e1, e2, e3);
  }
}

extern "C" void kernel_launch(void* const* d_in, const int* in_sizes, int n_in,
                              void* d_out, int out_size, void* d_ws,
                              size_t ws_size, hipStream_t stream) {
  const float* x_user = (const float*)d_in[0];
  const float* x_item = (const float*)d_in[1];
  const int* ei_u2i = (const int*)d_in[2];
  const int* ei_i2u = (const int*)d_in[3];
  const float* ea_u2i = (const float*)d_in[4];
  const float* ea_i2u = (const float*)d_in[5];
  const float* W_src = (const float*)d_in[6];
  const float* W_dst = (const float*)d_in[7];
  const float* W_edge = (const float*)d_in[8];
  const float* att_src = (const float*)d_in[9];
  const float* att_dst = (const float*)d_in[10];
  const float* att_edge = (const float*)d_in[11];
  const float* bias = (const float*)d_in[12];
  const float* ln_g = (const float*)d_in[13];
  const float* ln_b = (const float*)d_in[14];

  char* w = (char*)d_ws;
  auto alloc = [&](size_t bytes) {
    void* p = w;
    w += (bytes + 255) & ~(size_t)255;
    return p;
  };
  const size_t NBH = (size_t)NN * 128 * sizeof(short);
  short* hsU = (short*)alloc(NBH);
  short* hsI = (short*)alloc(NBH);
  short* hs2 = (short*)alloc(NBH);
  short* bufXI = (short*)alloc(NBH);
  short* bufXU = (short*)alloc(NBH);
  float* esU = (float*)alloc((size_t)NN * 4 * sizeof(float));
  float* esI = (float*)alloc((size_t)NN * 4 * sizeof(float));
  float* es2 = (float*)alloc((size_t)NN * 4 * sizeof(float));
  float* edC0 = (float*)alloc((size_t)NN * 4 * sizeof(float));
  float* edC1 = (float*)alloc((size_t)NN * 4 * sizeof(float));
  float* edL1 = (float*)alloc((size_t)NN * 4 * sizeof(float));
  unsigned long long* wbuf =
      (unsigned long long*)alloc((size_t)EE * sizeof(unsigned long long));
  short* Wt = (short*)alloc(128 * 128 * sizeof(short));
  short* foldB = (short*)alloc(128 * 16 * sizeof(short));
  float* Wea0 = (float*)alloc(64 * sizeof(float));
  float* Wea1 = (float*)alloc(64 * sizeof(float));
  float* Wea2 = (float*)alloc(64 * sizeof(float));
  float* WdaL1 = (float*)alloc(128 * 4 * sizeof(float));
  int* deg = (int*)alloc((size_t)NN * sizeof(int));
  int* cursor = (int*)alloc((size_t)NN * sizeof(int));
  int* bsums = (int*)alloc(512);
  int* offs_u2i = (int*)alloc((size_t)(NN + 4) * sizeof(int));
  int* offs_i2u = (int*)alloc((size_t)(NN + 4) * sizeof(int));
  int* ss_u2i = (int*)alloc((size_t)EE * sizeof(int));
  int* rk_u2i = (int*)alloc((size_t)EE * sizeof(int));
  int* ss_i2u = (int*)alloc((size_t)EE * sizeof(int));
  int* rk_i2u = (int*)alloc((size_t)EE * sizeof(int));

  const int SCAN_G = (NN + 1023) / 1024;
  const int EG = (EE + 255) / 256;
  const int GEMM_G = (NN / 16 + 3) / 4;

  auto build_csr = [&](const int* srcI, const int* dstI, int* offs, int* ss,
                       int* rank) {
    zero_f4<<<(NN / 4 + 255) / 256, 256, 0, stream>>>((float4*)deg, NN / 4);
    hist_k<<<EG, 256, 0, stream>>>(dstI, deg, EE);
    scan1_k<<<SCAN_G, 256, 0, stream>>>(deg, offs, bsums, NN);
    scan2_k<<<1, 128, 0, stream>>>(bsums, SCAN_G, offs + NN);
    scan3_k<<<SCAN_G, 256, 0, stream>>>(offs, bsums, cursor, NN);
    permute_k<<<EG, 256, 0, stream>>>(srcI, dstI, cursor, ss, rank, EE);
  };
  build_csr(ei_u2i, ei_u2i + EE, offs_u2i, ss_u2i, rk_u2i);
  build_csr(ei_i2u, ei_i2u + EE, offs_i2u, ss_i2u, rk_i2u);

  // param slices: conv0 = (l0,u2i) idx 0; conv1 = (l0,i2u) idx 1; conv2 = (l1,i2u) idx 3
  const float* Ws0 = W_src + 0 * 16384; const float* Ws1 = W_src + 1 * 16384;
  const float* Ws3 = W_src + 3 * 16384;
  const float* Wd0 = W_dst + 0 * 16384; const float* Wd1 = W_dst + 1 * 16384;
  const float* Wd3 = W_dst + 3 * 16384;
  const float* We0 = W_edge + 0 * 2048; const float* We1 = W_edge + 1 * 2048;
  const float* We3 = W_edge + 3 * 2048;
  const float* as0 = att_src + 0 * 128; const float* as1 = att_src + 1 * 128;
  const float* as3 = att_src + 3 * 128;
  const float* ad0 = att_dst + 0 * 128; const float* ad1 = att_dst + 1 * 128;
  const float* ad3 = att_dst + 3 * 128;
  const float* ae0 = att_edge + 0 * 128; const float* ae1 = att_edge + 1 * 128;
  const float* ae3 = att_edge + 3 * 128;

  // ---- GEMMs (each feature matrix read once; es for own conv + ed for sibling conv fused) ----
  // g0: A=x_user -> hsU, esU (Was from Ws0/as0), edC1 (Wda from Wd1/ad1); Wea0 side-fold
  prep_k<<<65, 256, 0, stream>>>(Ws0, as0, Wd1, ad1, We0, ae0, Wt, foldB, Wea0,
                                 nullptr);
  gemm_fused<true, true><<<GEMM_G, 256, 0, stream>>>(x_user, Wt, foldB, hsU,
                                                     esU, edC1, NN);
  // g1: A=x_item -> hsI, esI (Ws1/as1), edC0 (Wd0/ad0); Wea1
  prep_k<<<65, 256, 0, stream>>>(Ws1, as1, Wd0, ad0, We1, ae1, Wt, foldB, Wea1,
                                 nullptr);
  gemm_fused<true, true><<<GEMM_G, 256, 0, stream>>>(x_item, Wt, foldB, hsI,
                                                     esI, edC0, NN);

  // ---- layer 0, conv u2i (dst=item): LN params [0, item=1] ----
  alpha_k<<<EG, 256, 0, stream>>>(ei_u2i, ei_u2i + EE, rk_u2i, ea_u2i, esU,
                                  edC0, Wea0, wbuf, EE);
  gather_ln<true, false><<<(NN + 7) / 8, 256, 0, stream>>>(
      offs_u2i, ss_u2i, hsU, wbuf, bias + 0 * 128, ln_g + 1 * 128,
      ln_b + 1 * 128, bufXI, nullptr, nullptr, NN);
  // ---- layer 0, conv i2u (dst=user): LN params [0, user=0]; fuse ed for layer-1 ----
  // WdaL1 needed before this gather: fold it in g2's prep? No — prep2 runs later.
  // Fold WdaL1 now via a dedicated prep on conv2 params (also preps g2's Wt/foldB/Wea2).
  prep_k<<<65, 256, 0, stream>>>(Ws3, as3, Wd3, ad3, We3, ae3, Wt, foldB, Wea2,
                                 WdaL1);
  alpha_k<<<EG, 256, 0, stream>>>(ei_i2u, ei_i2u + EE, rk_i2u, ea_i2u, esI,
                                  edC1, Wea1, wbuf, EE);
  gather_ln<true, true><<<(NN + 7) / 8, 256, 0, stream>>>(
      offs_i2u, ss_i2u, hsI, wbuf, bias + 1 * 128, ln_g + 0 * 128,
      ln_b + 0 * 128, bufXU, WdaL1, edL1, NN);

  // ---- layer 1, conv i2u (src=bufXI items, dst=bufXU users): LN [1, user=2] ----
  gemm_fused<false, false><<<GEMM_G, 256, 0, stream>>>(bufXI, Wt, foldB, hs2,
                                                       es2, edC0, NN);
  alpha_k<<<EG, 256, 0, stream>>>(ei_i2u, ei_i2u + EE, rk_i2u, ea_i2u, es2,
                                  edL1, Wea2, wbuf, EE);
  gather_ln<false, false><<<(NN + 7) / 8, 256, 0, stream>>>(
      offs_i2u, ss_i2u, hs2, wbuf, bias + 3 * 128, ln_g + 2 * 128,
      ln_b + 2 * 128, d_out, nullptr, nullptr, NN);
}

// Round 5
// 566.893 us; speedup vs baseline: 6.4538x; 1.0595x over previous
//
#include <hip/hip_runtime.h>

#define NN 100000
#define EE 500000
#define LDSW 136     // padded bf16 row stride in LDS
#define GEMM_NG 1563 // ceil(100000/16/4)

typedef __attribute__((ext_vector_type(8))) short v8s;
typedef __attribute__((ext_vector_type(4))) float v4f;

// ---------- bf16 helpers (RNE) ----------
__device__ __forceinline__ short f2b(float f) {
  unsigned u = __float_as_uint(f);
  unsigned r = (u + 0x7FFFu + ((u >> 16) & 1u)) >> 16;
  return (short)r;
}
__device__ __forceinline__ float b2f(short s) {
  return __uint_as_float(((unsigned)(unsigned short)s) << 16);
}

// ---------- zero fill ----------
__global__ __launch_bounds__(256) void zero_f4(float4* __restrict__ p, long n4) {
  long i = (long)blockIdx.x * 256 + threadIdx.x;
  if (i < n4) p[i] = make_float4(0.f, 0.f, 0.f, 0.f);
}

// ---------- CSR build (both edge types concatenated: [u2i | i2u]) ----------
__global__ __launch_bounds__(256) void hist2_k(const int* __restrict__ ei_a,
                                               const int* __restrict__ ei_b,
                                               int* __restrict__ deg) {
  int e = blockIdx.x * 256 + threadIdx.x;
  if (e < EE)
    atomicAdd(&deg[ei_a[EE + e]], 1);
  else if (e < 2 * EE)
    atomicAdd(&deg[NN + ei_b[e]], 1);  // ei_b[EE + (e-EE)]
}

__global__ __launch_bounds__(256) void scan1_k(const int* __restrict__ deg,
                                               int* __restrict__ offs,
                                               int* __restrict__ bsums, int n) {
  __shared__ int sd[256];
  int t = threadIdx.x;
  int idx = blockIdx.x * 1024 + t * 4;
  int v0 = (idx < n) ? deg[idx] : 0;
  int v1 = (idx + 1 < n) ? deg[idx + 1] : 0;
  int v2 = (idx + 2 < n) ? deg[idx + 2] : 0;
  int v3 = (idx + 3 < n) ? deg[idx + 3] : 0;
  int s = v0 + v1 + v2 + v3;
  sd[t] = s;
  __syncthreads();
  for (int off = 1; off < 256; off <<= 1) {
    int x = (t >= off) ? sd[t - off] : 0;
    __syncthreads();
    sd[t] += x;
    __syncthreads();
  }
  int excl = sd[t] - s;
  if (idx < n) offs[idx] = excl;
  if (idx + 1 < n) offs[idx + 1] = excl + v0;
  if (idx + 2 < n) offs[idx + 2] = excl + v0 + v1;
  if (idx + 3 < n) offs[idx + 3] = excl + v0 + v1 + v2;
  if (t == 255) bsums[blockIdx.x] = sd[255];
}

__global__ __launch_bounds__(256) void scan2_k(int* __restrict__ bsums, int G,
                                               int* __restrict__ offs_last) {
  __shared__ int sd[256];
  int t = threadIdx.x;
  int v = (t < G) ? bsums[t] : 0;
  sd[t] = v;
  __syncthreads();
  for (int off = 1; off < 256; off <<= 1) {
    int x = (t >= off) ? sd[t - off] : 0;
    __syncthreads();
    sd[t] += x;
    __syncthreads();
  }
  int incl = sd[t];
  if (t < G) bsums[t] = incl - v;
  if (t == G - 1) *offs_last = incl;
}

__global__ __launch_bounds__(256) void scan3_k(int* __restrict__ offs,
                                               const int* __restrict__ bsums,
                                               int* __restrict__ cursor, int n) {
  int base = bsums[blockIdx.x];
  int idx = blockIdx.x * 1024 + threadIdx.x * 4;
#pragma unroll
  for (int i = 0; i < 4; ++i) {
    int id = idx + i;
    if (id < n) {
      int v = offs[id] + base;
      offs[id] = v;
      cursor[id] = v;
    }
  }
}

__global__ __launch_bounds__(256) void permute2_k(const int* __restrict__ ei_a,
                                                  const int* __restrict__ ei_b,
                                                  int* __restrict__ cursor,
                                                  int* __restrict__ ss,
                                                  int* __restrict__ rank) {
  int e = blockIdx.x * 256 + threadIdx.x;
  if (e >= 2 * EE) return;
  int s, dp;
  if (e < EE) {
    s = ei_a[e];
    dp = ei_a[EE + e];
  } else {
    s = ei_b[e - EE];
    dp = NN + ei_b[e];
  }
  int k = atomicAdd(&cursor[dp], 1);
  ss[k] = s;
  rank[e] = k;
}

// ---------- prep for all 3 convs: Wt bf16 transposes + [Was|Wda] folds + Wea + WdaL1 ----------
// conv c in {0,1,2} -> param slice pi {0,1,3}. foldB[c] cols 0-3 = Was(own),
// cols 4-7 = Wda of the conv whose dst-features equal this conv's A matrix.
__global__ __launch_bounds__(256) void prep_k(
    const float* __restrict__ W_src, const float* __restrict__ W_dst,
    const float* __restrict__ W_edge, const float* __restrict__ att_src,
    const float* __restrict__ att_dst, const float* __restrict__ att_edge,
    short* __restrict__ Wt, short* __restrict__ foldB, float* __restrict__ Wea,
    float* __restrict__ WdaL1) {
  int b = blockIdx.x, t = threadIdx.x;
  if (b < 192) {
    int c = b >> 6, bb = b & 63;
    int pi = (c == 2) ? 3 : c;
    const float* W = W_src + pi * 16384;
    int idx = bb * 256 + t;
    int k = idx >> 7, n = idx & 127;
    Wt[c * 16384 + n * 128 + k] = f2b(W[idx]);
    return;
  }
  int c = b - 192;
  int pi = (c == 2) ? 3 : c;
  int wd_pi = (c == 0) ? 1 : ((c == 1) ? 0 : 3);
  const float* W = W_src + pi * 16384;
  const float* as_ = att_src + pi * 128;
  const float* Wd = W_dst + wd_pi * 16384;
  const float* ad_ = att_dst + wd_pi * 128;
  const float* We = W_edge + pi * 2048;
  const float* ae_ = att_edge + pi * 128;
  short* fB = foldB + c * 2048;
  float* WeaC = Wea + c * 64;
  if (t < 128) {
#pragma unroll
    for (int h = 0; h < 4; ++h) {
      float s = 0.f;
      for (int cc = 0; cc < 32; ++cc)
        s += W[t * 128 + h * 32 + cc] * as_[h * 32 + cc];
      fB[t * 16 + h] = f2b(s);
    }
#pragma unroll
    for (int j = 8; j < 16; ++j) fB[t * 16 + j] = 0;
  } else {
    int k = t - 128;
    float o[4];
#pragma unroll
    for (int h = 0; h < 4; ++h) {
      float s = 0.f;
      for (int cc = 0; cc < 32; ++cc)
        s += Wd[k * 128 + h * 32 + cc] * ad_[h * 32 + cc];
      o[h] = s;
      fB[k * 16 + 4 + h] = f2b(s);
    }
    if (c == 2) ((float4*)WdaL1)[k] = make_float4(o[0], o[1], o[2], o[3]);
    if (k < 16) {
      float wv[4];
#pragma unroll
      for (int h = 0; h < 4; ++h) {
        float s = 0.f;
        for (int cc = 0; cc < 32; ++cc)
          s += We[k * 128 + h * 32 + cc] * ae_[h * 32 + cc];
        wv[h] = s;
      }
      ((float4*)WeaC)[k] = make_float4(wv[0], wv[1], wv[2], wv[3]);
    }
  }
}

// ---------- GEMM body: hs=A@W (bf16), es=A@Was, ed=A@Wda ----------
template <bool A_F32, bool STORE_ED>
__device__ __forceinline__ void gemm_body(int blk, const void* __restrict__ Ap,
                                          const short* __restrict__ Wt,
                                          const short* __restrict__ foldB16,
                                          short* __restrict__ hs,
                                          float* __restrict__ es,
                                          float* __restrict__ ed, int N,
                                          short* sW, short* sF, short* sC) {
  int t = threadIdx.x;
  {
    const int4* wp = (const int4*)Wt;
    for (int c = t; c < 2048; c += 256) {
      int row = c >> 4, col = c & 15;
      *(int4*)&sW[row * LDSW + col * 8] = wp[c];
    }
    ((int4*)sF)[t] = ((const int4*)foldB16)[t];
  }
  __syncthreads();
  int wid = t >> 6, lane = t & 63;
  long tile = (long)blk * 4 + wid;
  if (tile * 16 >= N) return;
  long row0 = tile * 16;
  int m = lane & 15, q = lane >> 4;
  v8s af[4];
  if (A_F32) {
    const float* arow = (const float*)Ap + (row0 + m) * 128 + q * 8;
#pragma unroll
    for (int kc = 0; kc < 4; ++kc) {
      float4 lo = *(const float4*)(arow + kc * 32);
      float4 hi = *(const float4*)(arow + kc * 32 + 4);
      v8s f;
      f[0] = f2b(lo.x); f[1] = f2b(lo.y); f[2] = f2b(lo.z); f[3] = f2b(lo.w);
      f[4] = f2b(hi.x); f[5] = f2b(hi.y); f[6] = f2b(hi.z); f[7] = f2b(hi.w);
      af[kc] = f;
    }
  } else {
    const short* arow = (const short*)Ap + (row0 + m) * 128 + q * 8;
#pragma unroll
    for (int kc = 0; kc < 4; ++kc) af[kc] = *(const v8s*)(arow + kc * 32);
  }
  v8s ff[4];
#pragma unroll
  for (int kc = 0; kc < 4; ++kc) {
    v8s f;
#pragma unroll
    for (int j = 0; j < 8; ++j) f[j] = sF[(kc * 32 + q * 8 + j) * 16 + m];
    ff[kc] = f;
  }
  v4f zero4 = {0.f, 0.f, 0.f, 0.f};
  v4f accf = zero4;
#pragma unroll
  for (int kc = 0; kc < 4; ++kc)
    accf = __builtin_amdgcn_mfma_f32_16x16x32_bf16(af[kc], ff[kc], accf, 0, 0, 0);
  v4f acc[8];
#pragma unroll
  for (int ct = 0; ct < 8; ++ct) {
    acc[ct] = zero4;
#pragma unroll
    for (int kc = 0; kc < 4; ++kc) {
      v8s bfr = *(const v8s*)&sW[(ct * 16 + m) * LDSW + kc * 32 + q * 8];
      acc[ct] =
          __builtin_amdgcn_mfma_f32_16x16x32_bf16(af[kc], bfr, acc[ct], 0, 0, 0);
    }
  }
#pragma unroll
  for (int r = 0; r < 4; ++r) {
    long row = row0 + q * 4 + r;
    if (m < 4)
      es[row * 4 + m] = accf[r];
    else if (STORE_ED && m < 8)
      ed[row * 4 + (m - 4)] = accf[r];
  }
  short* myC = sC + wid * 16 * LDSW;
#pragma unroll
  for (int ct = 0; ct < 8; ++ct)
#pragma unroll
    for (int r = 0; r < 4; ++r)
      myC[(q * 4 + r) * LDSW + ct * 16 + m] = f2b(acc[ct][r]);
  {
    int row = lane >> 2, part = lane & 3;
    short* dst = hs + (row0 + row) * 128 + part * 32;
#pragma unroll
    for (int i = 0; i < 4; ++i)
      *(int4*)(dst + i * 8) = *(int4*)&myC[row * LDSW + part * 32 + i * 8];
  }
}

// layer-0: both convs in one launch (block halves)
__global__ __launch_bounds__(256) void gemm01_k(
    const float* __restrict__ xu, const float* __restrict__ xi,
    const short* __restrict__ Wt, const short* __restrict__ foldB,
    short* __restrict__ hsU, short* __restrict__ hsI, float* __restrict__ esU,
    float* __restrict__ esI, float* __restrict__ edC0,
    float* __restrict__ edC1) {
  __shared__ short sW[128 * LDSW];
  __shared__ short sF[128 * 16];
  __shared__ short sC[4 * 16 * LDSW];
  int half = blockIdx.x >= GEMM_NG;
  int blk = blockIdx.x - (half ? GEMM_NG : 0);
  gemm_body<true, true>(blk, half ? (const void*)xi : (const void*)xu,
                        Wt + half * 16384, foldB + half * 2048,
                        half ? hsI : hsU, half ? esI : esU,
                        half ? edC0 : edC1, NN, sW, sF, sC);
}

__global__ __launch_bounds__(256) void gemm2_k(const short* __restrict__ A,
                                               const short* __restrict__ Wt,
                                               const short* __restrict__ foldB,
                                               short* __restrict__ hs,
                                               float* __restrict__ es) {
  __shared__ short sW[128 * LDSW];
  __shared__ short sF[128 * 16];
  __shared__ short sC[4 * 16 * LDSW];
  gemm_body<false, false>(blockIdx.x, A, Wt + 2 * 16384, foldB + 2 * 2048, hs,
                          es, nullptr, NN, sW, sF, sC);
}

// ---------- alpha: w4 = exp(leaky_relu(es[src]+ed[dst]+ea@Wea)) ----------
__device__ __forceinline__ float4 alpha_w(int s, int d,
                                          const float* __restrict__ ea_e,
                                          const float* __restrict__ es,
                                          const float* __restrict__ ed,
                                          const float* __restrict__ WeaC) {
  float4 es4 = ((const float4*)es)[s];
  float4 ed4 = ((const float4*)ed)[d];
  float acc[4] = {es4.x + ed4.x, es4.y + ed4.y, es4.z + ed4.z, es4.w + ed4.w};
  const float4* ea4 = (const float4*)ea_e;
#pragma unroll
  for (int qq = 0; qq < 4; ++qq) {
    float4 a = ea4[qq];
    float av[4] = {a.x, a.y, a.z, a.w};
#pragma unroll
    for (int i = 0; i < 4; ++i) {
      float4 w = ((const float4*)WeaC)[qq * 4 + i];
      acc[0] += av[i] * w.x;
      acc[1] += av[i] * w.y;
      acc[2] += av[i] * w.z;
      acc[3] += av[i] * w.w;
    }
  }
  float4 r;
#pragma unroll
  for (int h = 0; h < 4; ++h) {
    float v = acc[h];
    v = (v >= 0.f) ? v : 0.2f * v;
    ((float*)&r)[h] = __expf(v);  // alphas O(1): safe without max-subtraction
  }
  return r;
}

__global__ __launch_bounds__(256) void alpha01_k(
    const int* __restrict__ ei_a, const int* __restrict__ ei_b,
    const int* __restrict__ rank2, const float* __restrict__ ea_a,
    const float* __restrict__ ea_b, const float* __restrict__ esU,
    const float* __restrict__ esI, const float* __restrict__ edC0,
    const float* __restrict__ edC1, const float* __restrict__ Wea,
    float4* __restrict__ wbufF) {
  int e = blockIdx.x * 256 + threadIdx.x;
  if (e >= 2 * EE) return;
  bool h0 = e < EE;
  int el = h0 ? e : e - EE;
  const int* ei = h0 ? ei_a : ei_b;
  const float* ea = h0 ? ea_a : ea_b;
  const float* es = h0 ? esU : esI;
  const float* ed = h0 ? edC0 : edC1;
  const float* WeaC = Wea + (h0 ? 0 : 64);
  int s = ei[el], d = ei[EE + el];
  wbufF[rank2[e]] = alpha_w(s, d, ea + (long)el * 16, es, ed, WeaC);
}

__global__ __launch_bounds__(256) void alpha2_k(
    const int* __restrict__ ei_b, const int* __restrict__ rank2,
    const float* __restrict__ ea_b, const float* __restrict__ es2,
    const float* __restrict__ edL1, const float* __restrict__ Wea,
    float4* __restrict__ wbufF) {
  int e = blockIdx.x * 256 + threadIdx.x;
  if (e >= EE) return;
  int s = ei_b[e], d = ei_b[EE + e];
  wbufF[rank2[EE + e]] =
      alpha_w(s, d, ea_b + (long)e * 16, es2, edL1, Wea + 128);
}

// ---------- gather: weighted sum + bias + LN + ReLU ----------
// 32 lanes per dst node; lane j owns channels 4j..4j+3; head h=j>>3.
__device__ __forceinline__ void gather_body(
    int rs, int re, int j, int h, const int* __restrict__ ss,
    const short* __restrict__ hs, const float* __restrict__ wbufF,
    const float* __restrict__ bias, const float* __restrict__ gamma,
    const float* __restrict__ beta, float* y) {
  float den = 0.f, a0 = 0.f, a1 = 0.f, a2 = 0.f, a3 = 0.f;
  for (int k = rs; k < re; ++k) {
    int s = ss[k];
    float w = wbufF[(long)k * 4 + h];
    unsigned long long pp =
        *(const unsigned long long*)(hs + (long)s * 128 + j * 4);
    float v0 = b2f((short)(pp & 0xFFFF));
    float v1 = b2f((short)((pp >> 16) & 0xFFFF));
    float v2 = b2f((short)((pp >> 32) & 0xFFFF));
    float v3 = b2f((short)(pp >> 48));
    den += w;
    a0 += w * v0;
    a1 += w * v1;
    a2 += w * v2;
    a3 += w * v3;
  }
  float inv = 1.f / (den + 1e-16f);
  float4 b4 = ((const float4*)bias)[j];
  float o0 = a0 * inv + b4.x, o1 = a1 * inv + b4.y;
  float o2 = a2 * inv + b4.z, o3 = a3 * inv + b4.w;
  float s1 = o0 + o1 + o2 + o3;
  float s2 = o0 * o0 + o1 * o1 + o2 * o2 + o3 * o3;
#pragma unroll
  for (int mm = 1; mm <= 16; mm <<= 1) {
    s1 += __shfl_xor(s1, mm);
    s2 += __shfl_xor(s2, mm);
  }
  float mu = s1 * (1.f / 128.f);
  float var = s2 * (1.f / 128.f) - mu * mu;
  float rstd = rsqrtf(var + 1e-5f);
  float4 g4 = ((const float4*)gamma)[j];
  float4 be4 = ((const float4*)beta)[j];
  y[0] = fmaxf((o0 - mu) * rstd * g4.x + be4.x, 0.f);
  y[1] = fmaxf((o1 - mu) * rstd * g4.y + be4.y, 0.f);
  y[2] = fmaxf((o2 - mu) * rstd * g4.z + be4.z, 0.f);
  y[3] = fmaxf((o3 - mu) * rstd * g4.w + be4.w, 0.f);
}

// layer-0 both convs: g<NN item (conv0) -> bufXI; g>=NN user (conv1) -> bufXU + edL1 fuse
__global__ __launch_bounds__(256) void gather01_k(
    const int* __restrict__ offs2, const int* __restrict__ ss2,
    const short* __restrict__ hsU, const short* __restrict__ hsI,
    const float* __restrict__ wbufF, const float* __restrict__ bias,
    const float* __restrict__ ln_g, const float* __restrict__ ln_b,
    short* __restrict__ bufXI, short* __restrict__ bufXU,
    const float* __restrict__ WdaL1, float* __restrict__ edL1) {
  int t = threadIdx.x;
  int j = t & 31, h = j >> 3;
  int g = blockIdx.x * 8 + (t >> 5);
  if (g >= 2 * NN) return;
  bool item = g < NN;
  const short* hs = item ? hsU : hsI;
  const float* bi = bias + (item ? 0 : 128);
  const float* ga = ln_g + (item ? 128 : 0);
  const float* be = ln_b + (item ? 128 : 0);
  float y[4];
  gather_body(offs2[g], offs2[g + 1], j, h, ss2, hs, wbufF, bi, ga, be, y);
  long n = item ? g : g - NN;
  unsigned long long p = (unsigned long long)(unsigned short)f2b(y[0]) |
                         ((unsigned long long)(unsigned short)f2b(y[1]) << 16) |
                         ((unsigned long long)(unsigned short)f2b(y[2]) << 32) |
                         ((unsigned long long)(unsigned short)f2b(y[3]) << 48);
  ((unsigned long long*)(item ? bufXI : bufXU))[n * 32 + j] = p;
  if (!item) {  // fold next layer's ed = y @ WdaL1
    float e0 = 0.f, e1 = 0.f, e2 = 0.f, e3 = 0.f;
#pragma unroll
    for (int r = 0; r < 4; ++r) {
      float4 wr = ((const float4*)WdaL1)[j * 4 + r];
      e0 += y[r] * wr.x;
      e1 += y[r] * wr.y;
      e2 += y[r] * wr.z;
      e3 += y[r] * wr.w;
    }
#pragma unroll
    for (int mm = 1; mm <= 16; mm <<= 1) {
      e0 += __shfl_xor(e0, mm);
      e1 += __shfl_xor(e1, mm);
      e2 += __shfl_xor(e2, mm);
      e3 += __shfl_xor(e3, mm);
    }
    if (j == 0) ((float4*)edL1)[n] = make_float4(e0, e1, e2, e3);
  }
}

__global__ __launch_bounds__(256) void gather2_k(
    const int* __restrict__ offs, const int* __restrict__ ss2,
    const short* __restrict__ hs2, const float* __restrict__ wbufF,
    const float* __restrict__ bias, const float* __restrict__ ln_g,
    const float* __restrict__ ln_b, float* __restrict__ out) {
  int t = threadIdx.x;
  int j = t & 31, h = j >> 3;
  int n = blockIdx.x * 8 + (t >> 5);
  if (n >= NN) return;
  float y[4];
  gather_body(offs[n], offs[n + 1], j, h, ss2, hs2, wbufF, bias, ln_g, ln_b, y);
  ((float4*)out)[(long)n * 32 + j] = make_float4(y[0], y[1], y[2], y[3]);
}

extern "C" void kernel_launch(void* const* d_in, const int* in_sizes, int n_in,
                              void* d_out, int out_size, void* d_ws,
                              size_t ws_size, hipStream_t stream) {
  const float* x_user = (const float*)d_in[0];
  const float* x_item = (const float*)d_in[1];
  const int* ei_u2i = (const int*)d_in[2];
  const int* ei_i2u = (const int*)d_in[3];
  const float* ea_u2i = (const float*)d_in[4];
  const float* ea_i2u = (const float*)d_in[5];
  const float* W_src = (const float*)d_in[6];
  const float* W_dst = (const float*)d_in[7];
  const float* W_edge = (const float*)d_in[8];
  const float* att_src = (const float*)d_in[9];
  const float* att_dst = (const float*)d_in[10];
  const float* att_edge = (const float*)d_in[11];
  const float* bias = (const float*)d_in[12];
  const float* ln_g = (const float*)d_in[13];
  const float* ln_b = (const float*)d_in[14];

  char* w = (char*)d_ws;
  auto alloc = [&](size_t bytes) {
    void* p = w;
    w += (bytes + 255) & ~(size_t)255;
    return p;
  };
  const size_t NBH = (size_t)NN * 128 * sizeof(short);
  short* hsU = (short*)alloc(NBH);
  short* hsI = (short*)alloc(NBH);
  short* hs2 = (short*)alloc(NBH);
  short* bufXI = (short*)alloc(NBH);
  short* bufXU = (short*)alloc(NBH);
  float* esU = (float*)alloc((size_t)NN * 4 * sizeof(float));
  float* esI = (float*)alloc((size_t)NN * 4 * sizeof(float));
  float* es2 = (float*)alloc((size_t)NN * 4 * sizeof(float));
  float* edC0 = (float*)alloc((size_t)NN * 4 * sizeof(float));
  float* edC1 = (float*)alloc((size_t)NN * 4 * sizeof(float));
  float* edL1 = (float*)alloc((size_t)NN * 4 * sizeof(float));
  float4* wbufF = (float4*)alloc((size_t)2 * EE * sizeof(float4));  // 16MB
  short* Wt = (short*)alloc(3 * 16384 * sizeof(short));
  short* foldB = (short*)alloc(3 * 2048 * sizeof(short));
  float* Wea = (float*)alloc(3 * 64 * sizeof(float));
  float* WdaL1 = (float*)alloc(128 * 4 * sizeof(float));
  int* deg2 = (int*)alloc((size_t)2 * NN * sizeof(int));
  int* cursor2 = (int*)alloc((size_t)2 * NN * sizeof(int));
  int* bsums = (int*)alloc(1024);
  int* offs2 = (int*)alloc((size_t)(2 * NN + 8) * sizeof(int));
  int* ss2 = (int*)alloc((size_t)2 * EE * sizeof(int));
  int* rank2 = (int*)alloc((size_t)2 * EE * sizeof(int));

  const int E2G = (2 * EE + 255) / 256;            // 3907
  const int SCAN_G2 = (2 * NN + 1023) / 1024;      // 196

  // ---- CSR (both edge types, concatenated) : 6 launches ----
  zero_f4<<<(2 * NN / 4 + 255) / 256, 256, 0, stream>>>((float4*)deg2,
                                                        2 * NN / 4);
  hist2_k<<<E2G, 256, 0, stream>>>(ei_u2i, ei_i2u, deg2);
  scan1_k<<<SCAN_G2, 256, 0, stream>>>(deg2, offs2, bsums, 2 * NN);
  scan2_k<<<1, 256, 0, stream>>>(bsums, SCAN_G2, offs2 + 2 * NN);
  scan3_k<<<SCAN_G2, 256, 0, stream>>>(offs2, bsums, cursor2, 2 * NN);
  permute2_k<<<E2G, 256, 0, stream>>>(ei_u2i, ei_i2u, cursor2, ss2, rank2);

  // ---- params + layer 0 : 4 launches ----
  prep_k<<<195, 256, 0, stream>>>(W_src, W_dst, W_edge, att_src, att_dst,
                                  att_edge, Wt, foldB, Wea, WdaL1);
  gemm01_k<<<2 * GEMM_NG, 256, 0, stream>>>(x_user, x_item, Wt, foldB, hsU,
                                            hsI, esU, esI, edC0, edC1);
  alpha01_k<<<E2G, 256, 0, stream>>>(ei_u2i, ei_i2u, rank2, ea_u2i, ea_i2u,
                                     esU, esI, edC0, edC1, Wea, wbufF);
  gather01_k<<<2 * NN / 8, 256, 0, stream>>>(offs2, ss2, hsU, hsI,
                                             (const float*)wbufF, bias, ln_g,
                                             ln_b, bufXI, bufXU, WdaL1, edL1);

  // ---- layer 1 (user path only; item path dead) : 3 launches ----
  gemm2_k<<<GEMM_NG, 256, 0, stream>>>(bufXI, Wt, foldB, hs2, es2);
  alpha2_k<<<(EE + 255) / 256, 256, 0, stream>>>(ei_i2u, rank2, ea_i2u, es2,
                                                 edL1, Wea, wbufF);
  gather2_k<<<NN / 8, 256, 0, stream>>>(offs2 + NN, ss2, hs2,
                                        (const float*)wbufF, bias + 3 * 128,
                                        ln_g + 2 * 128, ln_b + 2 * 128,
                                        (float*)d_out);
}